// Round 1
// baseline (6476.883 us; speedup 1.0000x reference)
//
#include <hip/hip_runtime.h>

// Model dims
#define BB 512
#define LL 128
#define HH 768
#define LHID 256
#define TCHUNK 16
#define NCHUNK 8

__device__ __forceinline__ float fsig(float x) { return 1.f / (1.f + __expf(-x)); }
__device__ __forceinline__ float ftanh(float x) { return 1.f - 2.f / (__expf(2.f * x) + 1.f); }

// ---------------------------------------------------------------------------
// prep: transpose weights for coalesced access, fuse LSTM biases
// ---------------------------------------------------------------------------
__global__ __launch_bounds__(256) void prep_kernel(
    const float* __restrict__ w_hh, const float* __restrict__ b_ih, const float* __restrict__ b_hh,
    const float* __restrict__ w2, const float* __restrict__ w3, const float* __restrict__ w4,
    const float* __restrict__ fc1_w, const float* __restrict__ fc2_w, const float* __restrict__ fc3_w,
    float* __restrict__ w_hh_t, float* __restrict__ bias,
    float* __restrict__ w2t, float* __restrict__ w3t, float* __restrict__ w4t,
    float* __restrict__ fc1_wt, float* __restrict__ fc2_wt, float* __restrict__ fc3_wt) {
  int tid = blockIdx.x * 256 + threadIdx.x;  // grid = 1024*256 = 262144
  if (tid < 262144) {  // w_hh [1024][256] -> w_hh_t [256][1024]
    int k = tid >> 10, j = tid & 1023;
    w_hh_t[tid] = w_hh[j * 256 + k];
  }
  if (tid < 1024) bias[tid] = b_ih[tid] + b_hh[tid];
  if (tid < 81920) {  // w2 [64co][256ci][5] -> w2t [ci][dk][co]
    int ci = tid / 320, r = tid % 320, dk = r >> 6, co = r & 63;
    w2t[tid] = w2[(co * 256 + ci) * 5 + dk];
  }
  if (tid < 49152) {  // w3 [256co][64ci][3] -> w3t [ci][dk][co]
    int ci = tid / 768, r = tid % 768, dk = r >> 8, co = r & 255;
    w3t[tid] = w3[(co * 64 + ci) * 3 + dk];
  }
  if (tid < 4096) {  // w4 [16co][256ci] -> w4t [ci][co]
    int ci = tid >> 4, co = tid & 15;
    w4t[tid] = w4[co * 256 + ci];
  }
  if (tid < 65536) {  // fc1_w [128][512] -> fc1_wt [512][128]
    int k = tid >> 7, j = tid & 127;
    fc1_wt[tid] = fc1_w[j * 512 + k];
  }
  if (tid < 4096) {  // fc2_w [32][128] -> fc2_wt [128][32]
    int k = tid >> 5, j = tid & 31;
    fc2_wt[tid] = fc2_w[j * 128 + k];
  }
  if (tid < 64) {  // fc3_w [2][32] -> fc3_wt [32][2]
    int k = tid >> 1, j = tid & 1;
    fc3_wt[tid] = fc3_w[j * 32 + k];
  }
}

// ---------------------------------------------------------------------------
// gates GEMM: gates[m][n] = sum_k x[row(m)][k] * w_ih[n][k] + bias[n]
// m = b*16 + lc (chunk of 16 timesteps), M=8192, N=1024, K=768
// ---------------------------------------------------------------------------
__global__ __launch_bounds__(256) void gemm_gates(
    const float* __restrict__ x, const float* __restrict__ w_ih,
    const float* __restrict__ bias, float* __restrict__ gates, int l0) {
  __shared__ __align__(16) float As[16][132];
  __shared__ __align__(16) float Bs[16][132];
  int tid = threadIdx.x;
  int m0 = blockIdx.y << 7;
  int n0 = blockIdx.x << 7;
  int tx = tid & 15, ty = tid >> 4;
  float acc[8][8] = {};
  for (int kt = 0; kt < 768; kt += 16) {
#pragma unroll
    for (int u = 0; u < 2; u++) {
      int i = tid * 2 + u;          // float4 index, 512 total
      int row = i >> 2, kq = (i & 3) << 2;
      int m = m0 + row;
      int arow = ((m >> 4) << 7) + l0 + (m & 15);  // b*128 + l0 + lc
      const float4 va = *(const float4*)&x[arow * 768 + kt + kq];
      As[kq + 0][row] = va.x; As[kq + 1][row] = va.y;
      As[kq + 2][row] = va.z; As[kq + 3][row] = va.w;
      const float4 vb = *(const float4*)&w_ih[(n0 + row) * 768 + kt + kq];
      Bs[kq + 0][row] = vb.x; Bs[kq + 1][row] = vb.y;
      Bs[kq + 2][row] = vb.z; Bs[kq + 3][row] = vb.w;
    }
    __syncthreads();
#pragma unroll
    for (int kk = 0; kk < 16; kk++) {
      float a[8], b[8];
      *(float4*)&a[0] = *(const float4*)&As[kk][ty * 8];
      *(float4*)&a[4] = *(const float4*)&As[kk][ty * 8 + 4];
      *(float4*)&b[0] = *(const float4*)&Bs[kk][tx * 8];
      *(float4*)&b[4] = *(const float4*)&Bs[kk][tx * 8 + 4];
#pragma unroll
      for (int i2 = 0; i2 < 8; i2++)
#pragma unroll
        for (int j = 0; j < 8; j++) acc[i2][j] += a[i2] * b[j];
    }
    __syncthreads();
  }
  float bb[8];
#pragma unroll
  for (int j = 0; j < 8; j++) bb[j] = bias[n0 + tx * 8 + j];
#pragma unroll
  for (int i2 = 0; i2 < 8; i2++) {
    int m = m0 + ty * 8 + i2;
    float4 o0, o1;
    o0.x = acc[i2][0] + bb[0]; o0.y = acc[i2][1] + bb[1];
    o0.z = acc[i2][2] + bb[2]; o0.w = acc[i2][3] + bb[3];
    o1.x = acc[i2][4] + bb[4]; o1.y = acc[i2][5] + bb[5];
    o1.z = acc[i2][6] + bb[6]; o1.w = acc[i2][7] + bb[7];
    *(float4*)&gates[m * 1024 + n0 + tx * 8] = o0;
    *(float4*)&gates[m * 1024 + n0 + tx * 8 + 4] = o1;
  }
}

// ---------------------------------------------------------------------------
// LSTM recurrence, batch-partitioned (4 rows/block), 16 steps per launch.
// w_t is w_hh transposed to [k][j] (k-major) for coalesced streaming.
// Thread t owns hidden unit t (all 4 gates) for each of its 4 rows.
// ---------------------------------------------------------------------------
__global__ __launch_bounds__(256) void lstm_chunk(
    const float* __restrict__ gates, const float* __restrict__ w_t,
    float* __restrict__ h_state, float* __restrict__ c_state, float* __restrict__ hsum,
    float* __restrict__ z, int first, int last) {
  __shared__ float hl[4][256];
  int t = threadIdx.x;
  int r0 = blockIdx.x * 4;
  float c[4], hs[4];
#pragma unroll
  for (int r = 0; r < 4; r++) {
    float hv;
    if (first) { hv = 0.f; c[r] = 0.f; hs[r] = 0.f; }
    else {
      hv = h_state[(r0 + r) * 256 + t];
      c[r] = c_state[(r0 + r) * 256 + t];
      hs[r] = hsum[(r0 + r) * 256 + t];
    }
    hl[r][t] = hv;
  }
  __syncthreads();
  for (int lc = 0; lc < TCHUNK; lc++) {
    float a0[4] = {}, a1[4] = {}, a2[4] = {}, a3[4] = {};
#pragma unroll 4
    for (int k = 0; k < 256; k++) {
      float w0 = w_t[k * 1024 + t];
      float w1 = w_t[k * 1024 + 256 + t];
      float w2 = w_t[k * 1024 + 512 + t];
      float w3 = w_t[k * 1024 + 768 + t];
#pragma unroll
      for (int r = 0; r < 4; r++) {
        float hv = hl[r][k];
        a0[r] += hv * w0; a1[r] += hv * w1; a2[r] += hv * w2; a3[r] += hv * w3;
      }
    }
    float hnew[4];
#pragma unroll
    for (int r = 0; r < 4; r++) {
      const float* g = &gates[(((r0 + r) << 4) + lc) * 1024];
      float gi = a0[r] + g[t];
      float gf = a1[r] + g[256 + t];
      float gg = a2[r] + g[512 + t];
      float go = a3[r] + g[768 + t];
      float iv = fsig(gi), fv = fsig(gf), gv = ftanh(gg), ov = fsig(go);
      c[r] = fv * c[r] + iv * gv;
      float hv = ov * ftanh(c[r]);
      hs[r] += hv;
      hnew[r] = hv;
    }
    __syncthreads();   // all reads of hl done
#pragma unroll
    for (int r = 0; r < 4; r++) hl[r][t] = hnew[r];
    __syncthreads();   // hl ready for next step
  }
#pragma unroll
  for (int r = 0; r < 4; r++) {
    h_state[(r0 + r) * 256 + t] = hl[r][t];
    c_state[(r0 + r) * 256 + t] = c[r];
    hsum[(r0 + r) * 256 + t] = hs[r];
    if (last) z[(r0 + r) * 512 + t] = hs[r] * (1.f / 128.f);
  }
}

// ---------------------------------------------------------------------------
// conv1 (768ch, K=7, pad3) + bias + maxpool2 + relu -> out1 [512][256][64]
// Block = (batch b, 64-co group). Implicit im2col; X rows shared across taps.
// ---------------------------------------------------------------------------
__global__ __launch_bounds__(256) void conv1_kernel(
    const float* __restrict__ x, const float* __restrict__ w1,
    const float* __restrict__ b1, float* __restrict__ out1) {
  __shared__ float Xs[134 * 17];   // rows l=-3..130, 16 ci, pad 17
  __shared__ float Ws[64 * 113];   // 64 co x (16ci*7dk), pad 113
  int tid = threadIdx.x;
  int b = blockIdx.y;
  int co0 = blockIdx.x << 6;
  int tl = tid >> 4, tc = tid & 15;
  float acc[8][4] = {};
  for (int c0 = 0; c0 < 768; c0 += 16) {
    for (int f = tid; f < 536; f += 256) {  // 134 rows * 4 float4
      int row = f >> 2, q = (f & 3) << 2;
      int l = row - 3;
      float4 v = make_float4(0.f, 0.f, 0.f, 0.f);
      if (l >= 0 && l < 128) v = *(const float4*)&x[(b * 128 + l) * 768 + c0 + q];
      Xs[row * 17 + q + 0] = v.x; Xs[row * 17 + q + 1] = v.y;
      Xs[row * 17 + q + 2] = v.z; Xs[row * 17 + q + 3] = v.w;
    }
    for (int f = tid; f < 7168; f += 256) {  // 64co * 112
      int co = f / 112, r = f % 112;  // r = ci*7+dk
      Ws[co * 113 + r] = w1[(co0 + co) * 5376 + c0 * 7 + r];
    }
    __syncthreads();
#pragma unroll
    for (int ci = 0; ci < 16; ci++) {
      float xv[14];
#pragma unroll
      for (int u = 0; u < 14; u++) xv[u] = Xs[(tl * 8 + u) * 17 + ci];
#pragma unroll
      for (int dk = 0; dk < 7; dk++) {
        float wv[4];
#pragma unroll
        for (int j = 0; j < 4; j++) wv[j] = Ws[(tc + 16 * j) * 113 + ci * 7 + dk];
#pragma unroll
        for (int i = 0; i < 8; i++)
#pragma unroll
          for (int j = 0; j < 4; j++) acc[i][j] += xv[i + dk] * wv[j];
      }
    }
    __syncthreads();
  }
#pragma unroll
  for (int j = 0; j < 4; j++) {
    int co = co0 + tc + 16 * j;
    float bb = b1[co];
#pragma unroll
    for (int p = 0; p < 4; p++) {
      float v = fmaxf(acc[2 * p][j], acc[2 * p + 1][j]) + bb;
      out1[(b * 256 + co) * 64 + tl * 4 + p] = fmaxf(v, 0.f);
    }
  }
}

// ---------------------------------------------------------------------------
// conv2 (256->64, K=5, pad2) + pool2 + relu -> out2 [512][64][32]
// ---------------------------------------------------------------------------
__global__ __launch_bounds__(256) void conv2_kernel(
    const float* __restrict__ out1, const float* __restrict__ w2t,
    const float* __restrict__ b2, float* __restrict__ out2) {
  __shared__ float X2[32 * 68];
  __shared__ __align__(16) float W2[32 * 5 * 64];
  int tid = threadIdx.x;
  int b = blockIdx.x;
  int co = tid & 63, pg = tid >> 6;
  float acc[16] = {};
  for (int c0 = 0; c0 < 256; c0 += 32) {
    for (int f = tid; f < 512; f += 256) {  // 32ci * 16 float4
      int ci = f >> 4, q = (f & 15) << 2;
      float4 v = *(const float4*)&out1[(b * 256 + c0 + ci) * 64 + q];
      X2[ci * 68 + 2 + q + 0] = v.x; X2[ci * 68 + 2 + q + 1] = v.y;
      X2[ci * 68 + 2 + q + 2] = v.z; X2[ci * 68 + 2 + q + 3] = v.w;
    }
    if (tid < 32) { X2[tid * 68] = 0.f; X2[tid * 68 + 1] = 0.f; X2[tid * 68 + 66] = 0.f; X2[tid * 68 + 67] = 0.f; }
    for (int f = tid; f < 2560; f += 256)
      *(float4*)&W2[f * 4] = *(const float4*)&w2t[c0 * 320 + f * 4];
    __syncthreads();
    for (int ci = 0; ci < 32; ci++) {
      float xv[20];
#pragma unroll
      for (int u = 0; u < 20; u++) xv[u] = X2[ci * 68 + pg * 16 + u];
#pragma unroll
      for (int dk = 0; dk < 5; dk++) {
        float w = W2[(ci * 5 + dk) * 64 + co];
#pragma unroll
        for (int i = 0; i < 16; i++) acc[i] += xv[i + dk] * w;
      }
    }
    __syncthreads();
  }
  float bb = b2[co];
#pragma unroll
  for (int p = 0; p < 8; p++) {
    float v = fmaxf(acc[2 * p], acc[2 * p + 1]) + bb;
    out2[(b * 64 + co) * 32 + pg * 8 + p] = fmaxf(v, 0.f);
  }
}

// ---------------------------------------------------------------------------
// conv3 (64->256, K=3, pad1) + pool2 + relu -> out3 [512][256][16]
// ---------------------------------------------------------------------------
__global__ __launch_bounds__(256) void conv3_kernel(
    const float* __restrict__ out2, const float* __restrict__ w3t,
    const float* __restrict__ b3, float* __restrict__ out3) {
  __shared__ float X3[64 * 34];
  __shared__ __align__(16) float W3[16 * 3 * 256];
  int tid = threadIdx.x;
  int b = blockIdx.x;
  float acc[32] = {};
  for (int f = tid; f < 512; f += 256) {  // 64ci * 8 float4
    int ci = f >> 3, q = (f & 7) << 2;
    float4 v = *(const float4*)&out2[(b * 64 + ci) * 32 + q];
    X3[ci * 34 + 1 + q + 0] = v.x; X3[ci * 34 + 1 + q + 1] = v.y;
    X3[ci * 34 + 1 + q + 2] = v.z; X3[ci * 34 + 1 + q + 3] = v.w;
  }
  if (tid < 64) { X3[tid * 34] = 0.f; X3[tid * 34 + 33] = 0.f; }
  __syncthreads();
  for (int c0 = 0; c0 < 64; c0 += 16) {
    for (int f = tid; f < 3072; f += 256)
      *(float4*)&W3[f * 4] = *(const float4*)&w3t[c0 * 768 + f * 4];
    __syncthreads();
    for (int ci = 0; ci < 16; ci++) {
      float xv[34];
#pragma unroll
      for (int u = 0; u < 34; u++) xv[u] = X3[(c0 + ci) * 34 + u];
#pragma unroll
      for (int dk = 0; dk < 3; dk++) {
        float w = W3[(ci * 3 + dk) * 256 + tid];
#pragma unroll
        for (int i = 0; i < 32; i++) acc[i] += xv[i + dk] * w;
      }
    }
    __syncthreads();
  }
  float bb = b3[tid];
#pragma unroll
  for (int p = 0; p < 16; p++) {
    float v = fmaxf(acc[2 * p], acc[2 * p + 1]) + bb;
    out3[(b * 256 + tid) * 16 + p] = fmaxf(v, 0.f);
  }
}

// ---------------------------------------------------------------------------
// conv4 (256->16, K=1) + relu, flattened straight into z[:, 256:512]
// ---------------------------------------------------------------------------
__global__ __launch_bounds__(256) void conv4_kernel(
    const float* __restrict__ out3, const float* __restrict__ w4t,
    const float* __restrict__ b4, float* __restrict__ z) {
  __shared__ __align__(16) float X4[256 * 16];
  __shared__ __align__(16) float W4[256 * 16];
  int tid = threadIdx.x;
  int b = blockIdx.x;
  for (int f = tid; f < 1024; f += 256) {
    *(float4*)&X4[f * 4] = *(const float4*)&out3[b * 4096 + f * 4];
    *(float4*)&W4[f * 4] = *(const float4*)&w4t[f * 4];
  }
  __syncthreads();
  int co = tid >> 4, l = tid & 15;
  float acc = 0.f;
#pragma unroll 8
  for (int ci = 0; ci < 256; ci++) acc += X4[ci * 16 + l] * W4[ci * 16 + co];
  z[b * 512 + 256 + tid] = fmaxf(acc + b4[co], 0.f);
}

// ---------------------------------------------------------------------------
// MLP head: z[512] -> fc1(128) -> fc2(32) -> fc3(2), relu each
// ---------------------------------------------------------------------------
__global__ __launch_bounds__(128) void head_kernel(
    const float* __restrict__ z,
    const float* __restrict__ fc1_wt, const float* __restrict__ fc1_b,
    const float* __restrict__ fc2_wt, const float* __restrict__ fc2_b,
    const float* __restrict__ fc3_wt, const float* __restrict__ fc3_b,
    float* __restrict__ out) {
  __shared__ __align__(16) float zs[512];
  __shared__ float h1[128];
  __shared__ float h2[32];
  int tid = threadIdx.x;
  int b = blockIdx.x;
  *(float4*)&zs[tid * 4] = *(const float4*)&z[b * 512 + tid * 4];
  __syncthreads();
  float acc = 0.f;
#pragma unroll 8
  for (int k = 0; k < 512; k++) acc += zs[k] * fc1_wt[k * 128 + tid];
  h1[tid] = fmaxf(acc + fc1_b[tid], 0.f);
  __syncthreads();
  if (tid < 32) {
    float a2 = 0.f;
#pragma unroll 8
    for (int k = 0; k < 128; k++) a2 += h1[k] * fc2_wt[k * 32 + tid];
    h2[tid] = fmaxf(a2 + fc2_b[tid], 0.f);
  }
  __syncthreads();
  if (tid < 2) {
    float a3 = 0.f;
#pragma unroll
    for (int k = 0; k < 32; k++) a3 += h2[k] * fc3_wt[k * 2 + tid];
    out[b * 2 + tid] = fmaxf(a3 + fc3_b[tid], 0.f);
  }
}

// ---------------------------------------------------------------------------
extern "C" void kernel_launch(void* const* d_in, const int* in_sizes, int n_in,
                              void* d_out, int out_size, void* d_ws, size_t ws_size,
                              hipStream_t stream) {
  const float* x     = (const float*)d_in[0];
  const float* w_ih  = (const float*)d_in[1];
  const float* w_hh  = (const float*)d_in[2];
  const float* b_ih  = (const float*)d_in[3];
  const float* b_hh  = (const float*)d_in[4];
  const float* w1    = (const float*)d_in[5];
  const float* b1    = (const float*)d_in[6];
  const float* w2    = (const float*)d_in[7];
  const float* b2    = (const float*)d_in[8];
  const float* w3    = (const float*)d_in[9];
  const float* b3    = (const float*)d_in[10];
  const float* w4    = (const float*)d_in[11];
  const float* b4    = (const float*)d_in[12];
  const float* fc1_w = (const float*)d_in[13];
  const float* fc1_b = (const float*)d_in[14];
  const float* fc2_w = (const float*)d_in[15];
  const float* fc2_b = (const float*)d_in[16];
  const float* fc3_w = (const float*)d_in[17];
  const float* fc3_b = (const float*)d_in[18];
  float* out = (float*)d_out;

  float* W = (float*)d_ws;
  size_t o = 0;
  float* gates  = W + o; o += (size_t)8192 * 1024;  // 8,388,608
  float* w_hh_t = W + o; o += 262144;
  float* bias   = W + o; o += 1024;
  float* h_st   = W + o; o += 131072;
  float* c_st   = W + o; o += 131072;
  float* hsum   = W + o; o += 131072;
  float* z      = W + o; o += 262144;
  float* out1   = W + o; o += (size_t)512 * 256 * 64;  // 8,388,608
  float* out2   = W + o; o += (size_t)512 * 64 * 32;
  float* out3   = W + o; o += (size_t)512 * 256 * 16;
  float* w2t    = W + o; o += 81920;
  float* w3t    = W + o; o += 49152;
  float* w4t    = W + o; o += 4096;
  float* fc1_wt = W + o; o += 65536;
  float* fc2_wt = W + o; o += 4096;
  float* fc3_wt = W + o; o += 64;
  (void)ws_size; (void)in_sizes; (void)n_in; (void)out_size;

  prep_kernel<<<1024, 256, 0, stream>>>(w_hh, b_ih, b_hh, w2, w3, w4, fc1_w, fc2_w, fc3_w,
                                        w_hh_t, bias, w2t, w3t, w4t, fc1_wt, fc2_wt, fc3_wt);
  for (int c = 0; c < NCHUNK; c++) {
    gemm_gates<<<dim3(8, 64), 256, 0, stream>>>(x, w_ih, bias, gates, c * TCHUNK);
    lstm_chunk<<<128, 256, 0, stream>>>(gates, w_hh_t, h_st, c_st, hsum, z,
                                        c == 0 ? 1 : 0, c == NCHUNK - 1 ? 1 : 0);
  }
  conv1_kernel<<<dim3(4, 512), 256, 0, stream>>>(x, w1, b1, out1);
  conv2_kernel<<<512, 256, 0, stream>>>(out1, w2t, b2, out2);
  conv3_kernel<<<512, 256, 0, stream>>>(out2, w3t, b3, out3);
  conv4_kernel<<<512, 256, 0, stream>>>(out3, w4t, b4, z);
  head_kernel<<<512, 128, 0, stream>>>(z, fc1_wt, fc1_b, fc2_wt, fc2_b, fc3_wt, fc3_b, out);
}

// Round 2
// 4590.363 us; speedup vs baseline: 1.4110x; 1.4110x over previous
//
#include <hip/hip_runtime.h>

// Model dims
#define BB 512
#define LL 128
#define HH 768
#define LHID 256
#define TCHUNK 16
#define NCHUNK 8

typedef _Float16 h8 __attribute__((ext_vector_type(8)));
typedef _Float16 h4 __attribute__((ext_vector_type(4)));
typedef float f16acc __attribute__((ext_vector_type(16)));

#define APAD 72  // LDS row stride in halfs (64 data + 8 pad): 144B -> uniform bank spread

__device__ __forceinline__ float fsig(float x) { return 1.f / (1.f + __expf(-x)); }
__device__ __forceinline__ float ftanh(float x) { return 1.f - 2.f / (__expf(2.f * x) + 1.f); }

// ---------------------------------------------------------------------------
// prep: transpose weights for coalesced access, fuse LSTM biases,
//       split conv1 w into fp16 hi/lo (x64 scale), layout [p][dk][co][ci]
// ---------------------------------------------------------------------------
__global__ __launch_bounds__(256) void prep_kernel(
    const float* __restrict__ w_hh, const float* __restrict__ b_ih, const float* __restrict__ b_hh,
    const float* __restrict__ w1, const float* __restrict__ w2, const float* __restrict__ w3,
    const float* __restrict__ w4,
    const float* __restrict__ fc1_w, const float* __restrict__ fc2_w, const float* __restrict__ fc3_w,
    float* __restrict__ w_hh_t, float* __restrict__ bias,
    _Float16* __restrict__ w1s,
    float* __restrict__ w2t, float* __restrict__ w3t, float* __restrict__ w4t,
    float* __restrict__ fc1_wt, float* __restrict__ fc2_wt, float* __restrict__ fc3_wt) {
  int tid = blockIdx.x * 256 + threadIdx.x;  // grid = 5376*256 = 1376256
  if (tid < 1376256) {  // w1 [co][ci][dk] -> fp16 split hi/lo, layout [dk][co][ci], x64
    int dk = tid / 196608, r = tid % 196608, co = r / 768, ci = r % 768;
    float v = w1[((size_t)co * 768 + ci) * 7 + dk] * 64.f;
    _Float16 h = (_Float16)v;
    w1s[tid] = h;                              // (dk*256+co)*768+ci == tid
    w1s[1376256 + tid] = (_Float16)(v - (float)h);
  }
  if (tid < 262144) {  // w_hh [1024][256] -> w_hh_t [256][1024]
    int k = tid >> 10, j = tid & 1023;
    w_hh_t[tid] = w_hh[j * 256 + k];
  }
  if (tid < 1024) bias[tid] = b_ih[tid] + b_hh[tid];
  if (tid < 81920) {  // w2 [64co][256ci][5] -> w2t [ci][dk][co]
    int ci = tid / 320, r = tid % 320, dk = r >> 6, co = r & 63;
    w2t[tid] = w2[(co * 256 + ci) * 5 + dk];
  }
  if (tid < 49152) {  // w3 [256co][64ci][3] -> w3t [ci][dk][co]
    int ci = tid / 768, r = tid % 768, dk = r >> 8, co = r & 255;
    w3t[tid] = w3[(co * 64 + ci) * 3 + dk];
  }
  if (tid < 4096) {  // w4 [16co][256ci] -> w4t [ci][co]
    int ci = tid >> 4, co = tid & 15;
    w4t[tid] = w4[co * 256 + ci];
  }
  if (tid < 65536) {  // fc1_w [128][512] -> fc1_wt [512][128]
    int k = tid >> 7, j = tid & 127;
    fc1_wt[tid] = fc1_w[j * 512 + k];
  }
  if (tid < 4096) {  // fc2_w [32][128] -> fc2_wt [128][32]
    int k = tid >> 5, j = tid & 31;
    fc2_wt[tid] = fc2_w[j * 128 + k];
  }
  if (tid < 64) {  // fc3_w [2][32] -> fc3_wt [32][2]
    int k = tid >> 1, j = tid & 1;
    fc3_wt[tid] = fc3_w[j * 32 + k];
  }
}

// ---------------------------------------------------------------------------
// gates GEMM: gates[m][n] = sum_k x[row(m)][k] * w_ih[n][k] + bias[n]
// ---------------------------------------------------------------------------
__global__ __launch_bounds__(256) void gemm_gates(
    const float* __restrict__ x, const float* __restrict__ w_ih,
    const float* __restrict__ bias, float* __restrict__ gates, int l0) {
  __shared__ __align__(16) float As[16][132];
  __shared__ __align__(16) float Bs[16][132];
  int tid = threadIdx.x;
  int m0 = blockIdx.y << 7;
  int n0 = blockIdx.x << 7;
  int tx = tid & 15, ty = tid >> 4;
  float acc[8][8] = {};
  for (int kt = 0; kt < 768; kt += 16) {
#pragma unroll
    for (int u = 0; u < 2; u++) {
      int i = tid * 2 + u;
      int row = i >> 2, kq = (i & 3) << 2;
      int m = m0 + row;
      int arow = ((m >> 4) << 7) + l0 + (m & 15);
      const float4 va = *(const float4*)&x[arow * 768 + kt + kq];
      As[kq + 0][row] = va.x; As[kq + 1][row] = va.y;
      As[kq + 2][row] = va.z; As[kq + 3][row] = va.w;
      const float4 vb = *(const float4*)&w_ih[(n0 + row) * 768 + kt + kq];
      Bs[kq + 0][row] = vb.x; Bs[kq + 1][row] = vb.y;
      Bs[kq + 2][row] = vb.z; Bs[kq + 3][row] = vb.w;
    }
    __syncthreads();
#pragma unroll
    for (int kk = 0; kk < 16; kk++) {
      float a[8], b[8];
      *(float4*)&a[0] = *(const float4*)&As[kk][ty * 8];
      *(float4*)&a[4] = *(const float4*)&As[kk][ty * 8 + 4];
      *(float4*)&b[0] = *(const float4*)&Bs[kk][tx * 8];
      *(float4*)&b[4] = *(const float4*)&Bs[kk][tx * 8 + 4];
#pragma unroll
      for (int i2 = 0; i2 < 8; i2++)
#pragma unroll
        for (int j = 0; j < 8; j++) acc[i2][j] += a[i2] * b[j];
    }
    __syncthreads();
  }
  float bb[8];
#pragma unroll
  for (int j = 0; j < 8; j++) bb[j] = bias[n0 + tx * 8 + j];
#pragma unroll
  for (int i2 = 0; i2 < 8; i2++) {
    int m = m0 + ty * 8 + i2;
    float4 o0, o1;
    o0.x = acc[i2][0] + bb[0]; o0.y = acc[i2][1] + bb[1];
    o0.z = acc[i2][2] + bb[2]; o0.w = acc[i2][3] + bb[3];
    o1.x = acc[i2][4] + bb[4]; o1.y = acc[i2][5] + bb[5];
    o1.z = acc[i2][6] + bb[6]; o1.w = acc[i2][7] + bb[7];
    *(float4*)&gates[m * 1024 + n0 + tx * 8] = o0;
    *(float4*)&gates[m * 1024 + n0 + tx * 8 + 4] = o1;
  }
}

// ---------------------------------------------------------------------------
// LSTM recurrence, batch-partitioned (4 rows/block), 16 steps per launch.
// ---------------------------------------------------------------------------
__global__ __launch_bounds__(256) void lstm_chunk(
    const float* __restrict__ gates, const float* __restrict__ w_t,
    float* __restrict__ h_state, float* __restrict__ c_state, float* __restrict__ hsum,
    float* __restrict__ z, int first, int last) {
  __shared__ float hl[4][256];
  int t = threadIdx.x;
  int r0 = blockIdx.x * 4;
  float c[4], hs[4];
#pragma unroll
  for (int r = 0; r < 4; r++) {
    float hv;
    if (first) { hv = 0.f; c[r] = 0.f; hs[r] = 0.f; }
    else {
      hv = h_state[(r0 + r) * 256 + t];
      c[r] = c_state[(r0 + r) * 256 + t];
      hs[r] = hsum[(r0 + r) * 256 + t];
    }
    hl[r][t] = hv;
  }
  __syncthreads();
  for (int lc = 0; lc < TCHUNK; lc++) {
    float a0[4] = {}, a1[4] = {}, a2[4] = {}, a3[4] = {};
#pragma unroll 4
    for (int k = 0; k < 256; k++) {
      float w0 = w_t[k * 1024 + t];
      float w1 = w_t[k * 1024 + 256 + t];
      float w2 = w_t[k * 1024 + 512 + t];
      float w3 = w_t[k * 1024 + 768 + t];
#pragma unroll
      for (int r = 0; r < 4; r++) {
        float hv = hl[r][k];
        a0[r] += hv * w0; a1[r] += hv * w1; a2[r] += hv * w2; a3[r] += hv * w3;
      }
    }
    float hnew[4];
#pragma unroll
    for (int r = 0; r < 4; r++) {
      const float* g = &gates[(((r0 + r) << 4) + lc) * 1024];
      float gi = a0[r] + g[t];
      float gf = a1[r] + g[256 + t];
      float gg = a2[r] + g[512 + t];
      float go = a3[r] + g[768 + t];
      float iv = fsig(gi), fv = fsig(gf), gv = ftanh(gg), ov = fsig(go);
      c[r] = fv * c[r] + iv * gv;
      float hv = ov * ftanh(c[r]);
      hs[r] += hv;
      hnew[r] = hv;
    }
    __syncthreads();
#pragma unroll
    for (int r = 0; r < 4; r++) hl[r][t] = hnew[r];
    __syncthreads();
  }
#pragma unroll
  for (int r = 0; r < 4; r++) {
    h_state[(r0 + r) * 256 + t] = hl[r][t];
    c_state[(r0 + r) * 256 + t] = c[r];
    hsum[(r0 + r) * 256 + t] = hs[r];
    if (last) z[(r0 + r) * 512 + t] = hs[r] * (1.f / 128.f);
  }
}

// ---------------------------------------------------------------------------
// conv1 via MFMA fp16x2 split: out = relu(maxpool2(x *conv w1 + b1))
// Block = (co-half 128, batch). M=128 l-rows (halo 134), N=128 co, K=768ci x 7dk.
// 4 waves of 64x64, mfma_f32_32x32x16_f16, 3 split products (Ah*Bh+Ah*Bl+Al*Bh).
// w pre-scaled x64 at split (keeps w-lo out of fp16 denormals); epilogue /64.
// ---------------------------------------------------------------------------
__global__ __launch_bounds__(256, 2) void conv1_mfma(
    const float* __restrict__ x, const _Float16* __restrict__ w1s,
    const float* __restrict__ b1, float* __restrict__ out1) {
  __shared__ _Float16 Asp[2][134][APAD];  // [hi/lo][x row l0-3..l0+130][ci chunk 64]
  __shared__ _Float16 Bsp[2][128][APAD];  // [hi/lo][co 128][ci chunk 64]
  int tid = threadIdx.x;
  int b = blockIdx.y;
  int coh = blockIdx.x;  // co0 = coh*128
  int lane = tid & 63, w = tid >> 6;
  int wm = (w & 1) * 64, wn = (w >> 1) * 64;
  int r32 = lane & 31, hw8 = (lane >> 5) * 8;
  f16acc acc[2][2];
#pragma unroll
  for (int mm = 0; mm < 2; mm++)
#pragma unroll
    for (int nn = 0; nn < 2; nn++) acc[mm][nn] = (f16acc)(0.f);

  for (int cc = 0; cc < 12; cc++) {
    int ci0 = cc * 64;
    __syncthreads();  // prev iteration's reads of Asp/Bsp complete
    // stage A: 134 rows x 64 ci, fp32 -> fp16 hi/lo
    for (int f = tid; f < 134 * 16; f += 256) {
      int row = f >> 4, c4 = (f & 15) << 2;
      int l = row - 3;
      float4 v = make_float4(0.f, 0.f, 0.f, 0.f);
      if (l >= 0 && l < 128) v = *(const float4*)&x[((size_t)b * 128 + l) * 768 + ci0 + c4];
      h4 hi, lo;
      hi[0] = (_Float16)v.x; lo[0] = (_Float16)(v.x - (float)hi[0]);
      hi[1] = (_Float16)v.y; lo[1] = (_Float16)(v.y - (float)hi[1]);
      hi[2] = (_Float16)v.z; lo[2] = (_Float16)(v.z - (float)hi[2]);
      hi[3] = (_Float16)v.w; lo[3] = (_Float16)(v.w - (float)hi[3]);
      *(h4*)&Asp[0][row][c4] = hi;
      *(h4*)&Asp[1][row][c4] = lo;
    }
    for (int dk = 0; dk < 7; dk++) {
      if (dk) __syncthreads();  // prev dk's reads of Bsp complete
      // stage B(dk, ci chunk): 2 parts x 128 co x 64 ci
      for (int f = tid; f < 2048; f += 256) {
        int p = f >> 10, r = f & 1023, co = r >> 3, g = (r & 7) << 3;
        h8 v = *(const h8*)&w1s[(size_t)p * 1376256 +
                                ((size_t)dk * 256 + coh * 128 + co) * 768 + ci0 + g];
        *(h8*)&Bsp[p][co][g] = v;
      }
      __syncthreads();  // staging visible
      int ar = wm + r32 + dk;  // A_lds row = out_l + dk (x row out_l+dk-3)
      int br = wn + r32;
#pragma unroll
      for (int ks = 0; ks < 4; ks++) {
        int k = ks * 16 + hw8;
        h8 ah[2], al[2], bh[2], bl[2];
        ah[0] = *(const h8*)&Asp[0][ar][k];
        ah[1] = *(const h8*)&Asp[0][ar + 32][k];
        al[0] = *(const h8*)&Asp[1][ar][k];
        al[1] = *(const h8*)&Asp[1][ar + 32][k];
        bh[0] = *(const h8*)&Bsp[0][br][k];
        bh[1] = *(const h8*)&Bsp[0][br + 32][k];
        bl[0] = *(const h8*)&Bsp[1][br][k];
        bl[1] = *(const h8*)&Bsp[1][br + 32][k];
#pragma unroll
        for (int mm = 0; mm < 2; mm++)
#pragma unroll
          for (int nn = 0; nn < 2; nn++) {
            acc[mm][nn] = __builtin_amdgcn_mfma_f32_32x32x16_f16(ah[mm], bh[nn], acc[mm][nn], 0, 0, 0);
            acc[mm][nn] = __builtin_amdgcn_mfma_f32_32x32x16_f16(ah[mm], bl[nn], acc[mm][nn], 0, 0, 0);
            acc[mm][nn] = __builtin_amdgcn_mfma_f32_32x32x16_f16(al[mm], bh[nn], acc[mm][nn], 0, 0, 0);
          }
      }
    }
  }
  // epilogue: /64 scale, +bias, pool adjacent l rows (= adjacent acc regs), relu
  // C/D layout 32x32: col = lane&31, row = (reg&3) + 8*(reg>>2) + 4*(lane>>5)
#pragma unroll
  for (int mm = 0; mm < 2; mm++)
#pragma unroll
    for (int nn = 0; nn < 2; nn++) {
      int co = coh * 128 + wn + nn * 32 + r32;
      float bb = b1[co];
      size_t obase = ((size_t)b * 256 + co) * 64;
#pragma unroll
      for (int i = 0; i < 8; i++) {
        int rb = ((i & 1) << 1) + ((i >> 1) << 3) + (hw8 >> 1);  // row of reg 2i
        float v = fmaxf(acc[mm][nn][2 * i], acc[mm][nn][2 * i + 1]) * (1.f / 64.f) + bb;
        out1[obase + ((wm + mm * 32 + rb) >> 1)] = fmaxf(v, 0.f);
      }
    }
}

// ---------------------------------------------------------------------------
// conv2 (256->64, K=5, pad2) + pool2 + relu -> out2 [512][64][32]
// ---------------------------------------------------------------------------
__global__ __launch_bounds__(256) void conv2_kernel(
    const float* __restrict__ out1, const float* __restrict__ w2t,
    const float* __restrict__ b2, float* __restrict__ out2) {
  __shared__ float X2[32 * 68];
  __shared__ __align__(16) float W2[32 * 5 * 64];
  int tid = threadIdx.x;
  int b = blockIdx.x;
  int co = tid & 63, pg = tid >> 6;
  float acc[16] = {};
  for (int c0 = 0; c0 < 256; c0 += 32) {
    for (int f = tid; f < 512; f += 256) {
      int ci = f >> 4, q = (f & 15) << 2;
      float4 v = *(const float4*)&out1[(b * 256 + c0 + ci) * 64 + q];
      X2[ci * 68 + 2 + q + 0] = v.x; X2[ci * 68 + 2 + q + 1] = v.y;
      X2[ci * 68 + 2 + q + 2] = v.z; X2[ci * 68 + 2 + q + 3] = v.w;
    }
    if (tid < 32) { X2[tid * 68] = 0.f; X2[tid * 68 + 1] = 0.f; X2[tid * 68 + 66] = 0.f; X2[tid * 68 + 67] = 0.f; }
    for (int f = tid; f < 2560; f += 256)
      *(float4*)&W2[f * 4] = *(const float4*)&w2t[c0 * 320 + f * 4];
    __syncthreads();
    for (int ci = 0; ci < 32; ci++) {
      float xv[20];
#pragma unroll
      for (int u = 0; u < 20; u++) xv[u] = X2[ci * 68 + pg * 16 + u];
#pragma unroll
      for (int dk = 0; dk < 5; dk++) {
        float w = W2[(ci * 5 + dk) * 64 + co];
#pragma unroll
        for (int i = 0; i < 16; i++) acc[i] += xv[i + dk] * w;
      }
    }
    __syncthreads();
  }
  float bb = b2[co];
#pragma unroll
  for (int p = 0; p < 8; p++) {
    float v = fmaxf(acc[2 * p], acc[2 * p + 1]) + bb;
    out2[(b * 64 + co) * 32 + pg * 8 + p] = fmaxf(v, 0.f);
  }
}

// ---------------------------------------------------------------------------
// conv3 (64->256, K=3, pad1) + pool2 + relu -> out3 [512][256][16]
// ---------------------------------------------------------------------------
__global__ __launch_bounds__(256) void conv3_kernel(
    const float* __restrict__ out2, const float* __restrict__ w3t,
    const float* __restrict__ b3, float* __restrict__ out3) {
  __shared__ float X3[64 * 34];
  __shared__ __align__(16) float W3[16 * 3 * 256];
  int tid = threadIdx.x;
  int b = blockIdx.x;
  float acc[32] = {};
  for (int f = tid; f < 512; f += 256) {
    int ci = f >> 3, q = (f & 7) << 2;
    float4 v = *(const float4*)&out2[(b * 64 + ci) * 32 + q];
    X3[ci * 34 + 1 + q + 0] = v.x; X3[ci * 34 + 1 + q + 1] = v.y;
    X3[ci * 34 + 1 + q + 2] = v.z; X3[ci * 34 + 1 + q + 3] = v.w;
  }
  if (tid < 64) { X3[tid * 34] = 0.f; X3[tid * 34 + 33] = 0.f; }
  __syncthreads();
  for (int c0 = 0; c0 < 64; c0 += 16) {
    for (int f = tid; f < 3072; f += 256)
      *(float4*)&W3[f * 4] = *(const float4*)&w3t[c0 * 768 + f * 4];
    __syncthreads();
    for (int ci = 0; ci < 16; ci++) {
      float xv[34];
#pragma unroll
      for (int u = 0; u < 34; u++) xv[u] = X3[(c0 + ci) * 34 + u];
#pragma unroll
      for (int dk = 0; dk < 3; dk++) {
        float w = W3[(ci * 3 + dk) * 256 + tid];
#pragma unroll
        for (int i = 0; i < 32; i++) acc[i] += xv[i + dk] * w;
      }
    }
    __syncthreads();
  }
  float bb = b3[tid];
#pragma unroll
  for (int p = 0; p < 16; p++) {
    float v = fmaxf(acc[2 * p], acc[2 * p + 1]) + bb;
    out3[(b * 256 + tid) * 16 + p] = fmaxf(v, 0.f);
  }
}

// ---------------------------------------------------------------------------
// conv4 (256->16, K=1) + relu, flattened straight into z[:, 256:512]
// ---------------------------------------------------------------------------
__global__ __launch_bounds__(256) void conv4_kernel(
    const float* __restrict__ out3, const float* __restrict__ w4t,
    const float* __restrict__ b4, float* __restrict__ z) {
  __shared__ __align__(16) float X4[256 * 16];
  __shared__ __align__(16) float W4[256 * 16];
  int tid = threadIdx.x;
  int b = blockIdx.x;
  for (int f = tid; f < 1024; f += 256) {
    *(float4*)&X4[f * 4] = *(const float4*)&out3[b * 4096 + f * 4];
    *(float4*)&W4[f * 4] = *(const float4*)&w4t[f * 4];
  }
  __syncthreads();
  int co = tid >> 4, l = tid & 15;
  float acc = 0.f;
#pragma unroll 8
  for (int ci = 0; ci < 256; ci++) acc += X4[ci * 16 + l] * W4[ci * 16 + co];
  z[b * 512 + 256 + tid] = fmaxf(acc + b4[co], 0.f);
}

// ---------------------------------------------------------------------------
// MLP head
// ---------------------------------------------------------------------------
__global__ __launch_bounds__(128) void head_kernel(
    const float* __restrict__ z,
    const float* __restrict__ fc1_wt, const float* __restrict__ fc1_b,
    const float* __restrict__ fc2_wt, const float* __restrict__ fc2_b,
    const float* __restrict__ fc3_wt, const float* __restrict__ fc3_b,
    float* __restrict__ out) {
  __shared__ __align__(16) float zs[512];
  __shared__ float h1[128];
  __shared__ float h2[32];
  int tid = threadIdx.x;
  int b = blockIdx.x;
  *(float4*)&zs[tid * 4] = *(const float4*)&z[b * 512 + tid * 4];
  __syncthreads();
  float acc = 0.f;
#pragma unroll 8
  for (int k = 0; k < 512; k++) acc += zs[k] * fc1_wt[k * 128 + tid];
  h1[tid] = fmaxf(acc + fc1_b[tid], 0.f);
  __syncthreads();
  if (tid < 32) {
    float a2 = 0.f;
#pragma unroll 8
    for (int k = 0; k < 128; k++) a2 += h1[k] * fc2_wt[k * 32 + tid];
    h2[tid] = fmaxf(a2 + fc2_b[tid], 0.f);
  }
  __syncthreads();
  if (tid < 2) {
    float a3 = 0.f;
#pragma unroll
    for (int k = 0; k < 32; k++) a3 += h2[k] * fc3_wt[k * 2 + tid];
    out[b * 2 + tid] = fmaxf(a3 + fc3_b[tid], 0.f);
  }
}

// ---------------------------------------------------------------------------
extern "C" void kernel_launch(void* const* d_in, const int* in_sizes, int n_in,
                              void* d_out, int out_size, void* d_ws, size_t ws_size,
                              hipStream_t stream) {
  const float* x     = (const float*)d_in[0];
  const float* w_ih  = (const float*)d_in[1];
  const float* w_hh  = (const float*)d_in[2];
  const float* b_ih  = (const float*)d_in[3];
  const float* b_hh  = (const float*)d_in[4];
  const float* w1    = (const float*)d_in[5];
  const float* b1    = (const float*)d_in[6];
  const float* w2    = (const float*)d_in[7];
  const float* b2    = (const float*)d_in[8];
  const float* w3    = (const float*)d_in[9];
  const float* b3    = (const float*)d_in[10];
  const float* w4    = (const float*)d_in[11];
  const float* b4    = (const float*)d_in[12];
  const float* fc1_w = (const float*)d_in[13];
  const float* fc1_b = (const float*)d_in[14];
  const float* fc2_w = (const float*)d_in[15];
  const float* fc2_b = (const float*)d_in[16];
  const float* fc3_w = (const float*)d_in[17];
  const float* fc3_b = (const float*)d_in[18];
  float* out = (float*)d_out;

  float* W = (float*)d_ws;
  size_t o = 0;
  float* gates  = W + o; o += (size_t)8192 * 1024;
  float* w_hh_t = W + o; o += 262144;
  float* bias   = W + o; o += 1024;
  float* h_st   = W + o; o += 131072;
  float* c_st   = W + o; o += 131072;
  float* hsum   = W + o; o += 131072;
  float* z      = W + o; o += 262144;
  float* out1   = W + o; o += (size_t)512 * 256 * 64;
  float* out2   = W + o; o += (size_t)512 * 64 * 32;
  float* out3   = W + o; o += (size_t)512 * 256 * 16;
  float* w2t    = W + o; o += 81920;
  float* w3t    = W + o; o += 49152;
  float* w4t    = W + o; o += 4096;
  float* fc1_wt = W + o; o += 65536;
  float* fc2_wt = W + o; o += 4096;
  float* fc3_wt = W + o; o += 64;
  // w1 fp16 split (5.5 MB) aliases out3 (8.4 MB): conv1 reads it strictly
  // before conv3 writes out3 (stream order), so the overlap is safe.
  _Float16* w1s = (_Float16*)out3;
  (void)ws_size; (void)in_sizes; (void)n_in; (void)out_size;

  prep_kernel<<<5376, 256, 0, stream>>>(w_hh, b_ih, b_hh, w1, w2, w3, w4, fc1_w, fc2_w, fc3_w,
                                        w_hh_t, bias, w1s, w2t, w3t, w4t, fc1_wt, fc2_wt, fc3_wt);
  for (int c = 0; c < NCHUNK; c++) {
    gemm_gates<<<dim3(8, 64), 256, 0, stream>>>(x, w_ih, bias, gates, c * TCHUNK);
    lstm_chunk<<<128, 256, 0, stream>>>(gates, w_hh_t, h_st, c_st, hsum, z,
                                        c == 0 ? 1 : 0, c == NCHUNK - 1 ? 1 : 0);
  }
  conv1_mfma<<<dim3(2, 512), 256, 0, stream>>>(x, w1s, b1, out1);
  conv2_kernel<<<512, 256, 0, stream>>>(out1, w2t, b2, out2);
  conv3_kernel<<<512, 256, 0, stream>>>(out2, w3t, b3, out3);
  conv4_kernel<<<512, 256, 0, stream>>>(out3, w4t, b4, z);
  head_kernel<<<512, 128, 0, stream>>>(z, fc1_wt, fc1_b, fc2_wt, fc2_b, fc3_wt, fc3_b, out);
}

// Round 3
// 3603.762 us; speedup vs baseline: 1.7973x; 1.2738x over previous
//
#include <hip/hip_runtime.h>

// Model dims
#define BB 512
#define LL 128
#define HH 768
#define LHID 256
#define TCHUNK 16
#define NCHUNK 8

typedef _Float16 h8 __attribute__((ext_vector_type(8)));
typedef _Float16 h4 __attribute__((ext_vector_type(4)));
typedef float f16acc __attribute__((ext_vector_type(16)));

#define APAD 72  // LDS row stride in halfs

__device__ __forceinline__ float fsig(float x) { return 1.f / (1.f + __expf(-x)); }
__device__ __forceinline__ float ftanh(float x) { return 1.f - 2.f / (__expf(2.f * x) + 1.f); }

// ---------------------------------------------------------------------------
// prep: weight transposes / fp16 splits / LSTM bias fuse
// ---------------------------------------------------------------------------
__global__ __launch_bounds__(256) void prep_kernel(
    const float* __restrict__ w_ih, const float* __restrict__ w_hh,
    const float* __restrict__ b_ih, const float* __restrict__ b_hh,
    const float* __restrict__ w1, const float* __restrict__ w2, const float* __restrict__ w3,
    const float* __restrict__ w4,
    const float* __restrict__ fc1_w, const float* __restrict__ fc2_w, const float* __restrict__ fc3_w,
    float* __restrict__ w_q, float* __restrict__ bias,
    _Float16* __restrict__ w1s, _Float16* __restrict__ wihs,
    float* __restrict__ w2t, float* __restrict__ w3t, float* __restrict__ w4t,
    float* __restrict__ fc1_wt, float* __restrict__ fc2_wt, float* __restrict__ fc3_wt) {
  int tid = blockIdx.x * 256 + threadIdx.x;  // grid = 5376*256 = 1376256
  if (tid < 1376256) {  // w1 [co][ci][dk] -> fp16 split hi/lo, layout [dk][co][ci], x64
    int dk = tid / 196608, r = tid % 196608, co = r / 768, ci = r % 768;
    float v = w1[((size_t)co * 768 + ci) * 7 + dk] * 64.f;
    _Float16 h = (_Float16)v;
    w1s[tid] = h;
    w1s[1376256 + tid] = (_Float16)(v - (float)h);
  }
  if (tid < 786432) {  // w_ih [1024][768] -> fp16 split hi/lo, x64, layout [p][n][k]
    float v = w_ih[tid] * 64.f;
    _Float16 h = (_Float16)v;
    wihs[tid] = h;
    wihs[786432 + tid] = (_Float16)(v - (float)h);
  }
  if (tid < 65536) {  // w_hh [1024][256] -> w_q[k][unit] float4 (i,f,g,o)
    int k = tid >> 8, t = tid & 255;
    float4 wv;
    wv.x = w_hh[(0 * 256 + t) * 256 + k];
    wv.y = w_hh[(1 * 256 + t) * 256 + k];
    wv.z = w_hh[(2 * 256 + t) * 256 + k];
    wv.w = w_hh[(3 * 256 + t) * 256 + k];
    *(float4*)&w_q[tid * 4] = wv;
  }
  if (tid < 1024) bias[tid] = b_ih[tid] + b_hh[tid];
  if (tid < 81920) {  // w2 [64co][256ci][5] -> w2t [ci][dk][co]
    int ci = tid / 320, r = tid % 320, dk = r >> 6, co = r & 63;
    w2t[tid] = w2[(co * 256 + ci) * 5 + dk];
  }
  if (tid < 49152) {  // w3 [256co][64ci][3] -> w3t [ci][dk][co]
    int ci = tid / 768, r = tid % 768, dk = r >> 8, co = r & 255;
    w3t[tid] = w3[(co * 64 + ci) * 3 + dk];
  }
  if (tid < 4096) {  // w4 [16co][256ci] -> w4t [ci][co]
    int ci = tid >> 4, co = tid & 15;
    w4t[tid] = w4[co * 256 + ci];
  }
  if (tid < 65536) {  // fc1_w [128][512] -> fc1_wt [512][128]
    int k = tid >> 7, j = tid & 127;
    fc1_wt[tid] = fc1_w[j * 512 + k];
  }
  if (tid < 4096) {  // fc2_w [32][128] -> fc2_wt [128][32]
    int k = tid >> 5, j = tid & 31;
    fc2_wt[tid] = fc2_w[j * 128 + k];
  }
  if (tid < 64) {  // fc3_w [2][32] -> fc3_wt [32][2]
    int k = tid >> 1, j = tid & 1;
    fc3_wt[tid] = fc3_w[j * 32 + k];
  }
}

// ---------------------------------------------------------------------------
// gates GEMM via MFMA fp16x2 split. C[m][n] = x[row(m)] . w_ih[n] + bias[n].
// Output gathered float4-per-unit: gates[m*1024 + (n&255)*4 + (n>>8)].
// cmode=1: m = b*16+lc within a 16-step chunk; cmode=0: m = b*128+l (full).
// ---------------------------------------------------------------------------
__global__ __launch_bounds__(256, 2) void gemm_gates_mfma(
    const float* __restrict__ x, const _Float16* __restrict__ wihs,
    const float* __restrict__ bias, float* __restrict__ gates, int l0, int cmode) {
  __shared__ _Float16 Asp[2][128][APAD];
  __shared__ _Float16 Bsp[2][128][APAD];
  int tid = threadIdx.x;
  int m0 = blockIdx.y << 7, n0 = blockIdx.x << 7;
  int lane = tid & 63, w = tid >> 6;
  int wm = (w & 1) * 64, wn = (w >> 1) * 64;
  int r32 = lane & 31, hw8 = (lane >> 5) * 8;
  f16acc acc[2][2];
#pragma unroll
  for (int mm = 0; mm < 2; mm++)
#pragma unroll
    for (int nn = 0; nn < 2; nn++) acc[mm][nn] = (f16acc)(0.f);

  for (int kc = 0; kc < 12; kc++) {
    int k0 = kc * 64;
    if (kc) __syncthreads();
    // stage A: 128 rows x 64 k, fp32 -> fp16 hi/lo
    for (int f = tid; f < 2048; f += 256) {
      int row = f >> 4, c4 = (f & 15) << 2;
      int m = m0 + row;
      int xrow = cmode ? (((m >> 4) << 7) + l0 + (m & 15)) : m;
      float4 v = *(const float4*)&x[(size_t)xrow * 768 + k0 + c4];
      h4 hi, lo;
      hi[0] = (_Float16)v.x; lo[0] = (_Float16)(v.x - (float)hi[0]);
      hi[1] = (_Float16)v.y; lo[1] = (_Float16)(v.y - (float)hi[1]);
      hi[2] = (_Float16)v.z; lo[2] = (_Float16)(v.z - (float)hi[2]);
      hi[3] = (_Float16)v.w; lo[3] = (_Float16)(v.w - (float)hi[3]);
      *(h4*)&Asp[0][row][c4] = hi;
      *(h4*)&Asp[1][row][c4] = lo;
    }
    // stage B: 2 parts x 128 n x 64 k (pre-split)
    for (int f = tid; f < 2048; f += 256) {
      int p = f >> 10, r = f & 1023, n = r >> 3, g = (r & 7) << 3;
      *(h8*)&Bsp[p][n][g] = *(const h8*)&wihs[(size_t)p * 786432 + (size_t)(n0 + n) * 768 + k0 + g];
    }
    __syncthreads();
#pragma unroll
    for (int ks = 0; ks < 4; ks++) {
      int k = ks * 16 + hw8;
      h8 ah[2], al[2], bh[2], bl[2];
      ah[0] = *(const h8*)&Asp[0][wm + r32][k];
      ah[1] = *(const h8*)&Asp[0][wm + r32 + 32][k];
      al[0] = *(const h8*)&Asp[1][wm + r32][k];
      al[1] = *(const h8*)&Asp[1][wm + r32 + 32][k];
      bh[0] = *(const h8*)&Bsp[0][wn + r32][k];
      bh[1] = *(const h8*)&Bsp[0][wn + r32 + 32][k];
      bl[0] = *(const h8*)&Bsp[1][wn + r32][k];
      bl[1] = *(const h8*)&Bsp[1][wn + r32 + 32][k];
#pragma unroll
      for (int mm = 0; mm < 2; mm++)
#pragma unroll
        for (int nn = 0; nn < 2; nn++) {
          acc[mm][nn] = __builtin_amdgcn_mfma_f32_32x32x16_f16(ah[mm], bh[nn], acc[mm][nn], 0, 0, 0);
          acc[mm][nn] = __builtin_amdgcn_mfma_f32_32x32x16_f16(ah[mm], bl[nn], acc[mm][nn], 0, 0, 0);
          acc[mm][nn] = __builtin_amdgcn_mfma_f32_32x32x16_f16(al[mm], bh[nn], acc[mm][nn], 0, 0, 0);
        }
    }
  }
  // epilogue: /64, +bias, scatter to float4-per-unit layout
#pragma unroll
  for (int mm = 0; mm < 2; mm++)
#pragma unroll
    for (int nn = 0; nn < 2; nn++) {
      int n = n0 + wn + nn * 32 + r32;
      int u = n & 255, gate = n >> 8;
      float bb = bias[n];
#pragma unroll
      for (int reg = 0; reg < 16; reg++) {
        int row = (reg & 3) + 8 * (reg >> 2) + (hw8 >> 1);
        int m = m0 + wm + mm * 32 + row;
        gates[(size_t)m * 1024 + u * 4 + gate] = acc[mm][nn][reg] * (1.f / 64.f) + bb;
      }
    }
}

// ---------------------------------------------------------------------------
// LSTM recurrence: 128 blocks x 512 threads; block owns 4 batch rows.
// k-split halves (each sums 128 of 256 k), LDS partial reduce, each half
// finalizes 2 rows. w_q[k][unit] float4 streams from L2 (1 MB/block/step).
// ---------------------------------------------------------------------------
__global__ __launch_bounds__(512) void lstm_chunk(
    const float* __restrict__ gates, const float* __restrict__ w_q,
    float* __restrict__ h_state, float* __restrict__ c_state, float* __restrict__ hsum,
    float* __restrict__ z, int first, int last, int gB, int l0f) {
  __shared__ float hl[4][256];
  __shared__ __align__(16) float ps[4][256][4];  // [row][unit][gate]
  int tid = threadIdx.x;
  int t = tid & 255, half = tid >> 8;
  int r0 = blockIdx.x * 4;
  int rown = half * 2;   // rows this thread finalizes
  int rother = 2 - rown; // rows whose partials it hands off
  float c2[2], hs2[2];
#pragma unroll
  for (int rr = 0; rr < 2; rr++) {
    int r = rown + rr;
    float hv;
    if (first) { hv = 0.f; c2[rr] = 0.f; hs2[rr] = 0.f; }
    else {
      hv = h_state[(r0 + r) * 256 + t];
      c2[rr] = c_state[(r0 + r) * 256 + t];
      hs2[rr] = hsum[(r0 + r) * 256 + t];
    }
    hl[r][t] = hv;
  }
  __syncthreads();
  int kb = half << 7;
  for (int lc = 0; lc < TCHUNK; lc++) {
    float4 a[4];
#pragma unroll
    for (int r = 0; r < 4; r++) a[r] = make_float4(0.f, 0.f, 0.f, 0.f);
#pragma unroll 4
    for (int k = 0; k < 128; k++) {
      float4 wv = *(const float4*)&w_q[(size_t)(kb + k) * 1024 + t * 4];
#pragma unroll
      for (int r = 0; r < 4; r++) {
        float hv = hl[r][kb + k];
        a[r].x += hv * wv.x; a[r].y += hv * wv.y;
        a[r].z += hv * wv.z; a[r].w += hv * wv.w;
      }
    }
#pragma unroll
    for (int rr = 0; rr < 2; rr++)
      *(float4*)&ps[rother + rr][t][0] = a[rother + rr];
    __syncthreads();
    float hnew[2];
#pragma unroll
    for (int rr = 0; rr < 2; rr++) {
      int r = rown + rr;
      float4 p = *(const float4*)&ps[r][t][0];
      float4 g4 = *(const float4*)&gates[((size_t)(r0 + r) * gB + l0f + lc) * 1024 + t * 4];
      float gi = a[r].x + p.x + g4.x;
      float gf = a[r].y + p.y + g4.y;
      float gg = a[r].z + p.z + g4.z;
      float go = a[r].w + p.w + g4.w;
      float iv = fsig(gi), fv = fsig(gf), gv = ftanh(gg), ov = fsig(go);
      c2[rr] = fv * c2[rr] + iv * gv;
      float hv = ov * ftanh(c2[rr]);
      hs2[rr] += hv;
      hnew[rr] = hv;
    }
#pragma unroll
    for (int rr = 0; rr < 2; rr++) hl[rown + rr][t] = hnew[rr];
    __syncthreads();
  }
#pragma unroll
  for (int rr = 0; rr < 2; rr++) {
    int r = rown + rr;
    h_state[(r0 + r) * 256 + t] = hl[r][t];
    c_state[(r0 + r) * 256 + t] = c2[rr];
    hsum[(r0 + r) * 256 + t] = hs2[rr];
    if (last) z[(r0 + r) * 512 + t] = hs2[rr] * (1.f / 128.f);
  }
}

// ---------------------------------------------------------------------------
// conv1 via MFMA fp16x2 split (unchanged from round 2)
// ---------------------------------------------------------------------------
__global__ __launch_bounds__(256, 2) void conv1_mfma(
    const float* __restrict__ x, const _Float16* __restrict__ w1s,
    const float* __restrict__ b1, float* __restrict__ out1) {
  __shared__ _Float16 Asp[2][134][APAD];
  __shared__ _Float16 Bsp[2][128][APAD];
  int tid = threadIdx.x;
  int b = blockIdx.y;
  int coh = blockIdx.x;
  int lane = tid & 63, w = tid >> 6;
  int wm = (w & 1) * 64, wn = (w >> 1) * 64;
  int r32 = lane & 31, hw8 = (lane >> 5) * 8;
  f16acc acc[2][2];
#pragma unroll
  for (int mm = 0; mm < 2; mm++)
#pragma unroll
    for (int nn = 0; nn < 2; nn++) acc[mm][nn] = (f16acc)(0.f);

  for (int cc = 0; cc < 12; cc++) {
    int ci0 = cc * 64;
    __syncthreads();
    for (int f = tid; f < 134 * 16; f += 256) {
      int row = f >> 4, c4 = (f & 15) << 2;
      int l = row - 3;
      float4 v = make_float4(0.f, 0.f, 0.f, 0.f);
      if (l >= 0 && l < 128) v = *(const float4*)&x[((size_t)b * 128 + l) * 768 + ci0 + c4];
      h4 hi, lo;
      hi[0] = (_Float16)v.x; lo[0] = (_Float16)(v.x - (float)hi[0]);
      hi[1] = (_Float16)v.y; lo[1] = (_Float16)(v.y - (float)hi[1]);
      hi[2] = (_Float16)v.z; lo[2] = (_Float16)(v.z - (float)hi[2]);
      hi[3] = (_Float16)v.w; lo[3] = (_Float16)(v.w - (float)hi[3]);
      *(h4*)&Asp[0][row][c4] = hi;
      *(h4*)&Asp[1][row][c4] = lo;
    }
    for (int dk = 0; dk < 7; dk++) {
      if (dk) __syncthreads();
      for (int f = tid; f < 2048; f += 256) {
        int p = f >> 10, r = f & 1023, co = r >> 3, g = (r & 7) << 3;
        h8 v = *(const h8*)&w1s[(size_t)p * 1376256 +
                                ((size_t)dk * 256 + coh * 128 + co) * 768 + ci0 + g];
        *(h8*)&Bsp[p][co][g] = v;
      }
      __syncthreads();
      int ar = wm + r32 + dk;
      int br = wn + r32;
#pragma unroll
      for (int ks = 0; ks < 4; ks++) {
        int k = ks * 16 + hw8;
        h8 ah[2], al[2], bh[2], bl[2];
        ah[0] = *(const h8*)&Asp[0][ar][k];
        ah[1] = *(const h8*)&Asp[0][ar + 32][k];
        al[0] = *(const h8*)&Asp[1][ar][k];
        al[1] = *(const h8*)&Asp[1][ar + 32][k];
        bh[0] = *(const h8*)&Bsp[0][br][k];
        bh[1] = *(const h8*)&Bsp[0][br + 32][k];
        bl[0] = *(const h8*)&Bsp[1][br][k];
        bl[1] = *(const h8*)&Bsp[1][br + 32][k];
#pragma unroll
        for (int mm = 0; mm < 2; mm++)
#pragma unroll
          for (int nn = 0; nn < 2; nn++) {
            acc[mm][nn] = __builtin_amdgcn_mfma_f32_32x32x16_f16(ah[mm], bh[nn], acc[mm][nn], 0, 0, 0);
            acc[mm][nn] = __builtin_amdgcn_mfma_f32_32x32x16_f16(ah[mm], bl[nn], acc[mm][nn], 0, 0, 0);
            acc[mm][nn] = __builtin_amdgcn_mfma_f32_32x32x16_f16(al[mm], bh[nn], acc[mm][nn], 0, 0, 0);
          }
      }
    }
  }
#pragma unroll
  for (int mm = 0; mm < 2; mm++)
#pragma unroll
    for (int nn = 0; nn < 2; nn++) {
      int co = coh * 128 + wn + nn * 32 + r32;
      float bb = b1[co];
      size_t obase = ((size_t)b * 256 + co) * 64;
#pragma unroll
      for (int i = 0; i < 8; i++) {
        int rb = ((i & 1) << 1) + ((i >> 1) << 3) + (hw8 >> 1);
        float v = fmaxf(acc[mm][nn][2 * i], acc[mm][nn][2 * i + 1]) * (1.f / 64.f) + bb;
        out1[obase + ((wm + mm * 32 + rb) >> 1)] = fmaxf(v, 0.f);
      }
    }
}

// ---------------------------------------------------------------------------
// conv2 (256->64, K=5, pad2) + pool2 + relu -> out2 [512][64][32]
// ---------------------------------------------------------------------------
__global__ __launch_bounds__(256) void conv2_kernel(
    const float* __restrict__ out1, const float* __restrict__ w2t,
    const float* __restrict__ b2, float* __restrict__ out2) {
  __shared__ float X2[32 * 68];
  __shared__ __align__(16) float W2[32 * 5 * 64];
  int tid = threadIdx.x;
  int b = blockIdx.x;
  int co = tid & 63, pg = tid >> 6;
  float acc[16] = {};
  for (int c0 = 0; c0 < 256; c0 += 32) {
    for (int f = tid; f < 512; f += 256) {
      int ci = f >> 4, q = (f & 15) << 2;
      float4 v = *(const float4*)&out1[(b * 256 + c0 + ci) * 64 + q];
      X2[ci * 68 + 2 + q + 0] = v.x; X2[ci * 68 + 2 + q + 1] = v.y;
      X2[ci * 68 + 2 + q + 2] = v.z; X2[ci * 68 + 2 + q + 3] = v.w;
    }
    if (tid < 32) { X2[tid * 68] = 0.f; X2[tid * 68 + 1] = 0.f; X2[tid * 68 + 66] = 0.f; X2[tid * 68 + 67] = 0.f; }
    for (int f = tid; f < 2560; f += 256)
      *(float4*)&W2[f * 4] = *(const float4*)&w2t[c0 * 320 + f * 4];
    __syncthreads();
    for (int ci = 0; ci < 32; ci++) {
      float xv[20];
#pragma unroll
      for (int u = 0; u < 20; u++) xv[u] = X2[ci * 68 + pg * 16 + u];
#pragma unroll
      for (int dk = 0; dk < 5; dk++) {
        float w = W2[(ci * 5 + dk) * 64 + co];
#pragma unroll
        for (int i = 0; i < 16; i++) acc[i] += xv[i + dk] * w;
      }
    }
    __syncthreads();
  }
  float bb = b2[co];
#pragma unroll
  for (int p = 0; p < 8; p++) {
    float v = fmaxf(acc[2 * p], acc[2 * p + 1]) + bb;
    out2[(b * 64 + co) * 32 + pg * 8 + p] = fmaxf(v, 0.f);
  }
}

// ---------------------------------------------------------------------------
// conv3 (64->256, K=3, pad1) + pool2 + relu -> out3 [512][256][16]
// ---------------------------------------------------------------------------
__global__ __launch_bounds__(256) void conv3_kernel(
    const float* __restrict__ out2, const float* __restrict__ w3t,
    const float* __restrict__ b3, float* __restrict__ out3) {
  __shared__ float X3[64 * 34];
  __shared__ __align__(16) float W3[16 * 3 * 256];
  int tid = threadIdx.x;
  int b = blockIdx.x;
  float acc[32] = {};
  for (int f = tid; f < 512; f += 256) {
    int ci = f >> 3, q = (f & 7) << 2;
    float4 v = *(const float4*)&out2[(b * 64 + ci) * 32 + q];
    X3[ci * 34 + 1 + q + 0] = v.x; X3[ci * 34 + 1 + q + 1] = v.y;
    X3[ci * 34 + 1 + q + 2] = v.z; X3[ci * 34 + 1 + q + 3] = v.w;
  }
  if (tid < 64) { X3[tid * 34] = 0.f; X3[tid * 34 + 33] = 0.f; }
  __syncthreads();
  for (int c0 = 0; c0 < 64; c0 += 16) {
    for (int f = tid; f < 3072; f += 256)
      *(float4*)&W3[f * 4] = *(const float4*)&w3t[c0 * 768 + f * 4];
    __syncthreads();
    for (int ci = 0; ci < 16; ci++) {
      float xv[34];
#pragma unroll
      for (int u = 0; u < 34; u++) xv[u] = X3[(c0 + ci) * 34 + u];
#pragma unroll
      for (int dk = 0; dk < 3; dk++) {
        float w = W3[(ci * 3 + dk) * 256 + tid];
#pragma unroll
        for (int i = 0; i < 32; i++) acc[i] += xv[i + dk] * w;
      }
    }
    __syncthreads();
  }
  float bb = b3[tid];
#pragma unroll
  for (int p = 0; p < 16; p++) {
    float v = fmaxf(acc[2 * p], acc[2 * p + 1]) + bb;
    out3[(b * 256 + tid) * 16 + p] = fmaxf(v, 0.f);
  }
}

// ---------------------------------------------------------------------------
// conv4 (256->16, K=1) + relu -> z[:, 256:512]
// ---------------------------------------------------------------------------
__global__ __launch_bounds__(256) void conv4_kernel(
    const float* __restrict__ out3, const float* __restrict__ w4t,
    const float* __restrict__ b4, float* __restrict__ z) {
  __shared__ __align__(16) float X4[256 * 16];
  __shared__ __align__(16) float W4[256 * 16];
  int tid = threadIdx.x;
  int b = blockIdx.x;
  for (int f = tid; f < 1024; f += 256) {
    *(float4*)&X4[f * 4] = *(const float4*)&out3[b * 4096 + f * 4];
    *(float4*)&W4[f * 4] = *(const float4*)&w4t[f * 4];
  }
  __syncthreads();
  int co = tid >> 4, l = tid & 15;
  float acc = 0.f;
#pragma unroll 8
  for (int ci = 0; ci < 256; ci++) acc += X4[ci * 16 + l] * W4[ci * 16 + co];
  z[b * 512 + 256 + tid] = fmaxf(acc + b4[co], 0.f);
}

// ---------------------------------------------------------------------------
// MLP head
// ---------------------------------------------------------------------------
__global__ __launch_bounds__(128) void head_kernel(
    const float* __restrict__ z,
    const float* __restrict__ fc1_wt, const float* __restrict__ fc1_b,
    const float* __restrict__ fc2_wt, const float* __restrict__ fc2_b,
    const float* __restrict__ fc3_wt, const float* __restrict__ fc3_b,
    float* __restrict__ out) {
  __shared__ __align__(16) float zs[512];
  __shared__ float h1[128];
  __shared__ float h2[32];
  int tid = threadIdx.x;
  int b = blockIdx.x;
  *(float4*)&zs[tid * 4] = *(const float4*)&z[b * 512 + tid * 4];
  __syncthreads();
  float acc = 0.f;
#pragma unroll 8
  for (int k = 0; k < 512; k++) acc += zs[k] * fc1_wt[k * 128 + tid];
  h1[tid] = fmaxf(acc + fc1_b[tid], 0.f);
  __syncthreads();
  if (tid < 32) {
    float a2 = 0.f;
#pragma unroll 8
    for (int k = 0; k < 128; k++) a2 += h1[k] * fc2_wt[k * 32 + tid];
    h2[tid] = fmaxf(a2 + fc2_b[tid], 0.f);
  }
  __syncthreads();
  if (tid < 2) {
    float a3 = 0.f;
#pragma unroll
    for (int k = 0; k < 32; k++) a3 += h2[k] * fc3_wt[k * 2 + tid];
    out[b * 2 + tid] = fmaxf(a3 + fc3_b[tid], 0.f);
  }
}

// ---------------------------------------------------------------------------
extern "C" void kernel_launch(void* const* d_in, const int* in_sizes, int n_in,
                              void* d_out, int out_size, void* d_ws, size_t ws_size,
                              hipStream_t stream) {
  const float* x     = (const float*)d_in[0];
  const float* w_ih  = (const float*)d_in[1];
  const float* w_hh  = (const float*)d_in[2];
  const float* b_ih  = (const float*)d_in[3];
  const float* b_hh  = (const float*)d_in[4];
  const float* w1    = (const float*)d_in[5];
  const float* b1    = (const float*)d_in[6];
  const float* w2    = (const float*)d_in[7];
  const float* b2    = (const float*)d_in[8];
  const float* w3    = (const float*)d_in[9];
  const float* b3    = (const float*)d_in[10];
  const float* w4    = (const float*)d_in[11];
  const float* b4    = (const float*)d_in[12];
  const float* fc1_w = (const float*)d_in[13];
  const float* fc1_b = (const float*)d_in[14];
  const float* fc2_w = (const float*)d_in[15];
  const float* fc2_b = (const float*)d_in[16];
  const float* fc3_w = (const float*)d_in[17];
  const float* fc3_b = (const float*)d_in[18];
  float* out = (float*)d_out;

  // full mode: entire 65536x1024 gates in one GEMM (268 MB) if ws allows
  const size_t gfull = (size_t)65536 * 1024, gchunk = (size_t)8192 * 1024;
  const size_t rest = 262144 + 1024 + 3 * 131072 + 262144 + 8388608 + 1048576 +
                      2097152 + 81920 + 49152 + 4096 + 65536 + 4096 + 64 + 786432;
  int full = (ws_size >= (gfull + rest) * 4) ? 1 : 0;
  size_t gsz = full ? gfull : gchunk;

  float* W = (float*)d_ws;
  size_t o = 0;
  float* gates  = W + o; o += gsz;
  float* w_q    = W + o; o += 262144;
  float* bias   = W + o; o += 1024;
  float* h_st   = W + o; o += 131072;
  float* c_st   = W + o; o += 131072;
  float* hsum   = W + o; o += 131072;
  float* z      = W + o; o += 262144;
  float* out1   = W + o; o += (size_t)512 * 256 * 64;
  float* out2   = W + o; o += (size_t)512 * 64 * 32;
  float* out3   = W + o; o += (size_t)512 * 256 * 16;
  float* w2t    = W + o; o += 81920;
  float* w3t    = W + o; o += 49152;
  float* w4t    = W + o; o += 4096;
  float* fc1_wt = W + o; o += 65536;
  float* fc2_wt = W + o; o += 4096;
  float* fc3_wt = W + o; o += 64;
  _Float16* wihs = (_Float16*)(W + o); o += 786432;  // 2x1024x768 halfs
  // w1 fp16 split (5.5 MB) aliases out3 (8.4 MB): conv1 reads it strictly
  // before conv3 writes out3 (stream order), so the overlap is safe.
  _Float16* w1s = (_Float16*)out3;
  (void)in_sizes; (void)n_in; (void)out_size;

  prep_kernel<<<5376, 256, 0, stream>>>(w_ih, w_hh, b_ih, b_hh, w1, w2, w3, w4,
                                        fc1_w, fc2_w, fc3_w,
                                        w_q, bias, w1s, wihs, w2t, w3t, w4t,
                                        fc1_wt, fc2_wt, fc3_wt);
  if (full) {
    gemm_gates_mfma<<<dim3(8, 512), 256, 0, stream>>>(x, wihs, bias, gates, 0, 0);
    for (int c = 0; c < NCHUNK; c++)
      lstm_chunk<<<128, 512, 0, stream>>>(gates, w_q, h_st, c_st, hsum, z,
                                          c == 0, c == NCHUNK - 1, 128, c * TCHUNK);
  } else {
    for (int c = 0; c < NCHUNK; c++) {
      gemm_gates_mfma<<<dim3(8, 64), 256, 0, stream>>>(x, wihs, bias, gates, c * TCHUNK, 1);
      lstm_chunk<<<128, 512, 0, stream>>>(gates, w_q, h_st, c_st, hsum, z,
                                          c == 0, c == NCHUNK - 1, 16, 0);
    }
  }
  conv1_mfma<<<dim3(2, 512), 256, 0, stream>>>(x, w1s, b1, out1);
  conv2_kernel<<<512, 256, 0, stream>>>(out1, w2t, b2, out2);
  conv3_kernel<<<512, 256, 0, stream>>>(out2, w3t, b3, out3);
  conv4_kernel<<<512, 256, 0, stream>>>(out3, w4t, b4, z);
  head_kernel<<<512, 128, 0, stream>>>(z, fc1_wt, fc1_b, fc2_wt, fc2_b, fc3_wt, fc3_b, out);
}

// Round 4
// 3484.710 us; speedup vs baseline: 1.8587x; 1.0342x over previous
//
#include <hip/hip_runtime.h>

// Model dims
#define BB 512
#define LL 128
#define HH 768
#define LHID 256
#define TCHUNK 16
#define NCHUNK 8

typedef _Float16 h8 __attribute__((ext_vector_type(8)));
typedef _Float16 h4 __attribute__((ext_vector_type(4)));
typedef float f16acc __attribute__((ext_vector_type(16)));

#define APAD 72        // LDS row stride in halfs
#define XSP 50331648   // 65536*768, one part of split x

__device__ __forceinline__ float fsig(float x) { return 1.f / (1.f + __expf(-x)); }
__device__ __forceinline__ float ftanh(float x) { return 1.f - 2.f / (__expf(2.f * x) + 1.f); }

// ---------------------------------------------------------------------------
// xsplit: x fp32 -> fp16 hi/lo parts (unscaled; same numerics as round 2/3)
// ---------------------------------------------------------------------------
__global__ __launch_bounds__(256) void xsplit_kernel(
    const float* __restrict__ x, _Float16* __restrict__ xs) {
  size_t e = ((size_t)blockIdx.x * 256 + threadIdx.x) * 8;
  float4 a = *(const float4*)&x[e];
  float4 b = *(const float4*)&x[e + 4];
  h8 hi, lo;
  hi[0] = (_Float16)a.x; lo[0] = (_Float16)(a.x - (float)hi[0]);
  hi[1] = (_Float16)a.y; lo[1] = (_Float16)(a.y - (float)hi[1]);
  hi[2] = (_Float16)a.z; lo[2] = (_Float16)(a.z - (float)hi[2]);
  hi[3] = (_Float16)a.w; lo[3] = (_Float16)(a.w - (float)hi[3]);
  hi[4] = (_Float16)b.x; lo[4] = (_Float16)(b.x - (float)hi[4]);
  hi[5] = (_Float16)b.y; lo[5] = (_Float16)(b.y - (float)hi[5]);
  hi[6] = (_Float16)b.z; lo[6] = (_Float16)(b.z - (float)hi[6]);
  hi[7] = (_Float16)b.w; lo[7] = (_Float16)(b.w - (float)hi[7]);
  *(h8*)&xs[e] = hi;
  *(h8*)&xs[XSP + e] = lo;
}

// ---------------------------------------------------------------------------
// prep: weight transposes / fp16 splits / LSTM bias fuse
// wihs + biasg are pre-GATHERED: n' = u*4 + gate (so GEMM rows == gates layout)
// ---------------------------------------------------------------------------
__global__ __launch_bounds__(256) void prep_kernel(
    const float* __restrict__ w_ih, const float* __restrict__ w_hh,
    const float* __restrict__ b_ih, const float* __restrict__ b_hh,
    const float* __restrict__ w1, const float* __restrict__ w2, const float* __restrict__ w3,
    const float* __restrict__ w4,
    const float* __restrict__ fc1_w, const float* __restrict__ fc2_w, const float* __restrict__ fc3_w,
    float* __restrict__ w_q, float* __restrict__ biasg,
    _Float16* __restrict__ w1s, _Float16* __restrict__ wihs,
    float* __restrict__ w2t, float* __restrict__ w3t, float* __restrict__ w4t,
    float* __restrict__ fc1_wt, float* __restrict__ fc2_wt, float* __restrict__ fc3_wt) {
  int tid = blockIdx.x * 256 + threadIdx.x;  // grid = 5376*256 = 1376256
  if (tid < 1376256) {  // w1 [co][ci][dk] -> fp16 split hi/lo, layout [dk][co][ci], x64
    int dk = tid / 196608, r = tid % 196608, co = r / 768, ci = r % 768;
    float v = w1[((size_t)co * 768 + ci) * 7 + dk] * 64.f;
    _Float16 h = (_Float16)v;
    w1s[tid] = h;
    w1s[1376256 + tid] = (_Float16)(v - (float)h);
  }
  if (tid < 786432) {  // w_ih -> fp16 split hi/lo, x64, GATHERED rows n' = u*4+gate
    int np = tid / 768, k = tid % 768;
    int u = np >> 2, gate = np & 3;
    float v = w_ih[(size_t)(gate * 256 + u) * 768 + k] * 64.f;
    _Float16 h = (_Float16)v;
    wihs[tid] = h;
    wihs[786432 + tid] = (_Float16)(v - (float)h);
  }
  if (tid < 65536) {  // w_hh [1024][256] -> w_q[k][unit] float4 (i,f,g,o)
    int k = tid >> 8, t = tid & 255;
    float4 wv;
    wv.x = w_hh[(0 * 256 + t) * 256 + k];
    wv.y = w_hh[(1 * 256 + t) * 256 + k];
    wv.z = w_hh[(2 * 256 + t) * 256 + k];
    wv.w = w_hh[(3 * 256 + t) * 256 + k];
    *(float4*)&w_q[tid * 4] = wv;
  }
  if (tid < 1024) {  // gathered bias
    int u = tid >> 2, gate = tid & 3;
    biasg[tid] = b_ih[gate * 256 + u] + b_hh[gate * 256 + u];
  }
  if (tid < 81920) {  // w2 [64co][256ci][5] -> w2t [ci][dk][co]
    int ci = tid / 320, r = tid % 320, dk = r >> 6, co = r & 63;
    w2t[tid] = w2[(co * 256 + ci) * 5 + dk];
  }
  if (tid < 49152) {  // w3 [256co][64ci][3] -> w3t [ci][dk][co]
    int ci = tid / 768, r = tid % 768, dk = r >> 8, co = r & 255;
    w3t[tid] = w3[(co * 64 + ci) * 3 + dk];
  }
  if (tid < 4096) {  // w4 [16co][256ci] -> w4t [ci][co]
    int ci = tid >> 4, co = tid & 15;
    w4t[tid] = w4[co * 256 + ci];
  }
  if (tid < 65536) {  // fc1_w [128][512] -> fc1_wt [512][128]
    int k = tid >> 7, j = tid & 127;
    fc1_wt[tid] = fc1_w[j * 512 + k];
  }
  if (tid < 4096) {  // fc2_w [32][128] -> fc2_wt [128][32]
    int k = tid >> 5, j = tid & 31;
    fc2_wt[tid] = fc2_w[j * 128 + k];
  }
  if (tid < 64) {  // fc3_w [2][32] -> fc3_wt [32][2]
    int k = tid >> 1, j = tid & 1;
    fc3_wt[tid] = fc3_w[j * 32 + k];
  }
}

// ---------------------------------------------------------------------------
// gates GEMM via MFMA fp16x2 split, pre-split inputs.
// B rows pre-gathered (n' = u*4+gate) so C[m][n'] row-major == gates layout:
// epilogue stores are 32-lane-contiguous full cache lines.
// 1-D grid, XCD-aware decode: the 8 n-tiles of one m-tile share an XCD.
// ---------------------------------------------------------------------------
__global__ __launch_bounds__(256, 2) void gemm_gates_mfma(
    const _Float16* __restrict__ xs, const _Float16* __restrict__ wihs,
    const float* __restrict__ biasg, float* __restrict__ gates, int l0, int cmode) {
  __shared__ _Float16 Asp[2][128][APAD];
  __shared__ _Float16 Bsp[2][128][APAD];
  int tid = threadIdx.x;
  int gid = blockIdx.x;
  int mt = (gid & 7) + ((gid >> 6) << 3), nt = (gid >> 3) & 7;
  int m0 = mt << 7, n0 = nt << 7;
  int lane = tid & 63, w = tid >> 6;
  int wm = (w & 1) * 64, wn = (w >> 1) * 64;
  int r32 = lane & 31, hw8 = (lane >> 5) * 8;
  f16acc acc[2][2];
#pragma unroll
  for (int mm = 0; mm < 2; mm++)
#pragma unroll
    for (int nn = 0; nn < 2; nn++) acc[mm][nn] = (f16acc)(0.f);

  for (int kc = 0; kc < 12; kc++) {
    int k0 = kc * 64;
    if (kc) __syncthreads();
    // stage A: 2 parts x 128 rows x 64 k (pre-split, pure copy)
    for (int f = tid; f < 2048; f += 256) {
      int p = f >> 10, r = f & 1023, row = r >> 3, g = (r & 7) << 3;
      int m = m0 + row;
      int xrow = cmode ? (((m >> 4) << 7) + l0 + (m & 15)) : m;
      *(h8*)&Asp[p][row][g] = *(const h8*)&xs[(size_t)p * XSP + (size_t)xrow * 768 + k0 + g];
    }
    // stage B: 2 parts x 128 n' x 64 k (pre-split, gathered)
    for (int f = tid; f < 2048; f += 256) {
      int p = f >> 10, r = f & 1023, n = r >> 3, g = (r & 7) << 3;
      *(h8*)&Bsp[p][n][g] = *(const h8*)&wihs[(size_t)p * 786432 + (size_t)(n0 + n) * 768 + k0 + g];
    }
    __syncthreads();
#pragma unroll
    for (int ks = 0; ks < 4; ks++) {
      int k = ks * 16 + hw8;
      h8 ah[2], al[2], bh[2], bl[2];
      ah[0] = *(const h8*)&Asp[0][wm + r32][k];
      ah[1] = *(const h8*)&Asp[0][wm + r32 + 32][k];
      al[0] = *(const h8*)&Asp[1][wm + r32][k];
      al[1] = *(const h8*)&Asp[1][wm + r32 + 32][k];
      bh[0] = *(const h8*)&Bsp[0][wn + r32][k];
      bh[1] = *(const h8*)&Bsp[0][wn + r32 + 32][k];
      bl[0] = *(const h8*)&Bsp[1][wn + r32][k];
      bl[1] = *(const h8*)&Bsp[1][wn + r32 + 32][k];
#pragma unroll
      for (int mm = 0; mm < 2; mm++)
#pragma unroll
        for (int nn = 0; nn < 2; nn++) {
          acc[mm][nn] = __builtin_amdgcn_mfma_f32_32x32x16_f16(ah[mm], bh[nn], acc[mm][nn], 0, 0, 0);
          acc[mm][nn] = __builtin_amdgcn_mfma_f32_32x32x16_f16(ah[mm], bl[nn], acc[mm][nn], 0, 0, 0);
          acc[mm][nn] = __builtin_amdgcn_mfma_f32_32x32x16_f16(al[mm], bh[nn], acc[mm][nn], 0, 0, 0);
        }
    }
  }
  // epilogue: /64, +bias, contiguous row-major stores (full lines)
#pragma unroll
  for (int mm = 0; mm < 2; mm++)
#pragma unroll
    for (int nn = 0; nn < 2; nn++) {
      int n = n0 + wn + nn * 32 + r32;
      float bb = biasg[n];
#pragma unroll
      for (int reg = 0; reg < 16; reg++) {
        int row = (reg & 3) + 8 * (reg >> 2) + (hw8 >> 1);
        int m = m0 + wm + mm * 32 + row;
        gates[(size_t)m * 1024 + n] = acc[mm][nn][reg] * (1.f / 64.f) + bb;
      }
    }
}

// ---------------------------------------------------------------------------
// LSTM recurrence: 128 blocks x 512 threads; block owns 4 batch rows.
// ---------------------------------------------------------------------------
__global__ __launch_bounds__(512) void lstm_chunk(
    const float* __restrict__ gates, const float* __restrict__ w_q,
    float* __restrict__ h_state, float* __restrict__ c_state, float* __restrict__ hsum,
    float* __restrict__ z, int first, int last, int gB, int l0f) {
  __shared__ float hl[4][256];
  __shared__ __align__(16) float ps[4][256][4];  // [row][unit][gate]
  int tid = threadIdx.x;
  int t = tid & 255, half = tid >> 8;
  int r0 = blockIdx.x * 4;
  int rown = half * 2;
  int rother = 2 - rown;
  float c2[2], hs2[2];
#pragma unroll
  for (int rr = 0; rr < 2; rr++) {
    int r = rown + rr;
    float hv;
    if (first) { hv = 0.f; c2[rr] = 0.f; hs2[rr] = 0.f; }
    else {
      hv = h_state[(r0 + r) * 256 + t];
      c2[rr] = c_state[(r0 + r) * 256 + t];
      hs2[rr] = hsum[(r0 + r) * 256 + t];
    }
    hl[r][t] = hv;
  }
  __syncthreads();
  int kb = half << 7;
  for (int lc = 0; lc < TCHUNK; lc++) {
    float4 a[4];
#pragma unroll
    for (int r = 0; r < 4; r++) a[r] = make_float4(0.f, 0.f, 0.f, 0.f);
#pragma unroll 4
    for (int k = 0; k < 128; k++) {
      float4 wv = *(const float4*)&w_q[(size_t)(kb + k) * 1024 + t * 4];
#pragma unroll
      for (int r = 0; r < 4; r++) {
        float hv = hl[r][kb + k];
        a[r].x += hv * wv.x; a[r].y += hv * wv.y;
        a[r].z += hv * wv.z; a[r].w += hv * wv.w;
      }
    }
#pragma unroll
    for (int rr = 0; rr < 2; rr++)
      *(float4*)&ps[rother + rr][t][0] = a[rother + rr];
    __syncthreads();
    float hnew[2];
#pragma unroll
    for (int rr = 0; rr < 2; rr++) {
      int r = rown + rr;
      float4 p = *(const float4*)&ps[r][t][0];
      float4 g4 = *(const float4*)&gates[((size_t)(r0 + r) * gB + l0f + lc) * 1024 + t * 4];
      float gi = a[r].x + p.x + g4.x;
      float gf = a[r].y + p.y + g4.y;
      float gg = a[r].z + p.z + g4.z;
      float go = a[r].w + p.w + g4.w;
      float iv = fsig(gi), fv = fsig(gf), gv = ftanh(gg), ov = fsig(go);
      c2[rr] = fv * c2[rr] + iv * gv;
      float hv = ov * ftanh(c2[rr]);
      hs2[rr] += hv;
      hnew[rr] = hv;
    }
#pragma unroll
    for (int rr = 0; rr < 2; rr++) hl[rown + rr][t] = hnew[rr];
    __syncthreads();
  }
#pragma unroll
  for (int rr = 0; rr < 2; rr++) {
    int r = rown + rr;
    h_state[(r0 + r) * 256 + t] = hl[r][t];
    c_state[(r0 + r) * 256 + t] = c2[rr];
    hsum[(r0 + r) * 256 + t] = hs2[rr];
    if (last) z[(r0 + r) * 512 + t] = hs2[rr] * (1.f / 128.f);
  }
}

// ---------------------------------------------------------------------------
// conv1 via MFMA fp16x2 split; A-staging now reads pre-split xs (pure copy)
// ---------------------------------------------------------------------------
__global__ __launch_bounds__(256, 2) void conv1_mfma(
    const _Float16* __restrict__ xs, const _Float16* __restrict__ w1s,
    const float* __restrict__ b1, float* __restrict__ out1) {
  __shared__ _Float16 Asp[2][134][APAD];
  __shared__ _Float16 Bsp[2][128][APAD];
  int tid = threadIdx.x;
  int b = blockIdx.y;
  int coh = blockIdx.x;
  int lane = tid & 63, w = tid >> 6;
  int wm = (w & 1) * 64, wn = (w >> 1) * 64;
  int r32 = lane & 31, hw8 = (lane >> 5) * 8;
  f16acc acc[2][2];
#pragma unroll
  for (int mm = 0; mm < 2; mm++)
#pragma unroll
    for (int nn = 0; nn < 2; nn++) acc[mm][nn] = (f16acc)(0.f);

  for (int cc = 0; cc < 12; cc++) {
    int ci0 = cc * 64;
    __syncthreads();
    // stage A: 2 parts x 134 rows x 8 h8 groups = 2144 copies
    for (int f = tid; f < 2144; f += 256) {
      int p = f >= 1072;
      int r = f - p * 1072;
      int row = r >> 3, g = (r & 7) << 3;
      int l = row - 3;
      h8 v = (h8)(_Float16)0.f;
      if (l >= 0 && l < 128)
        v = *(const h8*)&xs[(size_t)p * XSP + ((size_t)b * 128 + l) * 768 + ci0 + g];
      *(h8*)&Asp[p][row][g] = v;
    }
    for (int dk = 0; dk < 7; dk++) {
      if (dk) __syncthreads();
      for (int f = tid; f < 2048; f += 256) {
        int p = f >> 10, r = f & 1023, co = r >> 3, g = (r & 7) << 3;
        h8 v = *(const h8*)&w1s[(size_t)p * 1376256 +
                                ((size_t)dk * 256 + coh * 128 + co) * 768 + ci0 + g];
        *(h8*)&Bsp[p][co][g] = v;
      }
      __syncthreads();
      int ar = wm + r32 + dk;
      int br = wn + r32;
#pragma unroll
      for (int ks = 0; ks < 4; ks++) {
        int k = ks * 16 + hw8;
        h8 ah[2], al[2], bh[2], bl[2];
        ah[0] = *(const h8*)&Asp[0][ar][k];
        ah[1] = *(const h8*)&Asp[0][ar + 32][k];
        al[0] = *(const h8*)&Asp[1][ar][k];
        al[1] = *(const h8*)&Asp[1][ar + 32][k];
        bh[0] = *(const h8*)&Bsp[0][br][k];
        bh[1] = *(const h8*)&Bsp[0][br + 32][k];
        bl[0] = *(const h8*)&Bsp[1][br][k];
        bl[1] = *(const h8*)&Bsp[1][br + 32][k];
#pragma unroll
        for (int mm = 0; mm < 2; mm++)
#pragma unroll
          for (int nn = 0; nn < 2; nn++) {
            acc[mm][nn] = __builtin_amdgcn_mfma_f32_32x32x16_f16(ah[mm], bh[nn], acc[mm][nn], 0, 0, 0);
            acc[mm][nn] = __builtin_amdgcn_mfma_f32_32x32x16_f16(ah[mm], bl[nn], acc[mm][nn], 0, 0, 0);
            acc[mm][nn] = __builtin_amdgcn_mfma_f32_32x32x16_f16(al[mm], bh[nn], acc[mm][nn], 0, 0, 0);
          }
      }
    }
  }
#pragma unroll
  for (int mm = 0; mm < 2; mm++)
#pragma unroll
    for (int nn = 0; nn < 2; nn++) {
      int co = coh * 128 + wn + nn * 32 + r32;
      float bb = b1[co];
      size_t obase = ((size_t)b * 256 + co) * 64;
#pragma unroll
      for (int i = 0; i < 8; i++) {
        int rb = ((i & 1) << 1) + ((i >> 1) << 3) + (hw8 >> 1);
        float v = fmaxf(acc[mm][nn][2 * i], acc[mm][nn][2 * i + 1]) * (1.f / 64.f) + bb;
        out1[obase + ((wm + mm * 32 + rb) >> 1)] = fmaxf(v, 0.f);
      }
    }
}

// ---------------------------------------------------------------------------
// conv2 (256->64, K=5, pad2) + pool2 + relu -> out2 [512][64][32]
// ---------------------------------------------------------------------------
__global__ __launch_bounds__(256) void conv2_kernel(
    const float* __restrict__ out1, const float* __restrict__ w2t,
    const float* __restrict__ b2, float* __restrict__ out2) {
  __shared__ float X2[32 * 68];
  __shared__ __align__(16) float W2[32 * 5 * 64];
  int tid = threadIdx.x;
  int b = blockIdx.x;
  int co = tid & 63, pg = tid >> 6;
  float acc[16] = {};
  for (int c0 = 0; c0 < 256; c0 += 32) {
    for (int f = tid; f < 512; f += 256) {
      int ci = f >> 4, q = (f & 15) << 2;
      float4 v = *(const float4*)&out1[(b * 256 + c0 + ci) * 64 + q];
      X2[ci * 68 + 2 + q + 0] = v.x; X2[ci * 68 + 2 + q + 1] = v.y;
      X2[ci * 68 + 2 + q + 2] = v.z; X2[ci * 68 + 2 + q + 3] = v.w;
    }
    if (tid < 32) { X2[tid * 68] = 0.f; X2[tid * 68 + 1] = 0.f; X2[tid * 68 + 66] = 0.f; X2[tid * 68 + 67] = 0.f; }
    for (int f = tid; f < 2560; f += 256)
      *(float4*)&W2[f * 4] = *(const float4*)&w2t[c0 * 320 + f * 4];
    __syncthreads();
    for (int ci = 0; ci < 32; ci++) {
      float xv[20];
#pragma unroll
      for (int u = 0; u < 20; u++) xv[u] = X2[ci * 68 + pg * 16 + u];
#pragma unroll
      for (int dk = 0; dk < 5; dk++) {
        float w = W2[(ci * 5 + dk) * 64 + co];
#pragma unroll
        for (int i = 0; i < 16; i++) acc[i] += xv[i + dk] * w;
      }
    }
    __syncthreads();
  }
  float bb = b2[co];
#pragma unroll
  for (int p = 0; p < 8; p++) {
    float v = fmaxf(acc[2 * p], acc[2 * p + 1]) + bb;
    out2[(b * 64 + co) * 32 + pg * 8 + p] = fmaxf(v, 0.f);
  }
}

// ---------------------------------------------------------------------------
// conv3 (64->256, K=3, pad1) + pool2 + relu -> out3 [512][256][16]
// ---------------------------------------------------------------------------
__global__ __launch_bounds__(256) void conv3_kernel(
    const float* __restrict__ out2, const float* __restrict__ w3t,
    const float* __restrict__ b3, float* __restrict__ out3) {
  __shared__ float X3[64 * 34];
  __shared__ __align__(16) float W3[16 * 3 * 256];
  int tid = threadIdx.x;
  int b = blockIdx.x;
  float acc[32] = {};
  for (int f = tid; f < 512; f += 256) {
    int ci = f >> 3, q = (f & 7) << 2;
    float4 v = *(const float4*)&out2[(b * 64 + ci) * 32 + q];
    X3[ci * 34 + 1 + q + 0] = v.x; X3[ci * 34 + 1 + q + 1] = v.y;
    X3[ci * 34 + 1 + q + 2] = v.z; X3[ci * 34 + 1 + q + 3] = v.w;
  }
  if (tid < 64) { X3[tid * 34] = 0.f; X3[tid * 34 + 33] = 0.f; }
  __syncthreads();
  for (int c0 = 0; c0 < 64; c0 += 16) {
    for (int f = tid; f < 3072; f += 256)
      *(float4*)&W3[f * 4] = *(const float4*)&w3t[c0 * 768 + f * 4];
    __syncthreads();
    for (int ci = 0; ci < 16; ci++) {
      float xv[34];
#pragma unroll
      for (int u = 0; u < 34; u++) xv[u] = X3[(c0 + ci) * 34 + u];
#pragma unroll
      for (int dk = 0; dk < 3; dk++) {
        float w = W3[(ci * 3 + dk) * 256 + tid];
#pragma unroll
        for (int i = 0; i < 32; i++) acc[i] += xv[i + dk] * w;
      }
    }
    __syncthreads();
  }
  float bb = b3[tid];
#pragma unroll
  for (int p = 0; p < 16; p++) {
    float v = fmaxf(acc[2 * p], acc[2 * p + 1]) + bb;
    out3[(b * 256 + tid) * 16 + p] = fmaxf(v, 0.f);
  }
}

// ---------------------------------------------------------------------------
// conv4 (256->16, K=1) + relu -> z[:, 256:512]
// ---------------------------------------------------------------------------
__global__ __launch_bounds__(256) void conv4_kernel(
    const float* __restrict__ out3, const float* __restrict__ w4t,
    const float* __restrict__ b4, float* __restrict__ z) {
  __shared__ __align__(16) float X4[256 * 16];
  __shared__ __align__(16) float W4[256 * 16];
  int tid = threadIdx.x;
  int b = blockIdx.x;
  for (int f = tid; f < 1024; f += 256) {
    *(float4*)&X4[f * 4] = *(const float4*)&out3[b * 4096 + f * 4];
    *(float4*)&W4[f * 4] = *(const float4*)&w4t[f * 4];
  }
  __syncthreads();
  int co = tid >> 4, l = tid & 15;
  float acc = 0.f;
#pragma unroll 8
  for (int ci = 0; ci < 256; ci++) acc += X4[ci * 16 + l] * W4[ci * 16 + co];
  z[b * 512 + 256 + tid] = fmaxf(acc + b4[co], 0.f);
}

// ---------------------------------------------------------------------------
// MLP head
// ---------------------------------------------------------------------------
__global__ __launch_bounds__(128) void head_kernel(
    const float* __restrict__ z,
    const float* __restrict__ fc1_wt, const float* __restrict__ fc1_b,
    const float* __restrict__ fc2_wt, const float* __restrict__ fc2_b,
    const float* __restrict__ fc3_wt, const float* __restrict__ fc3_b,
    float* __restrict__ out) {
  __shared__ __align__(16) float zs[512];
  __shared__ float h1[128];
  __shared__ float h2[32];
  int tid = threadIdx.x;
  int b = blockIdx.x;
  *(float4*)&zs[tid * 4] = *(const float4*)&z[b * 512 + tid * 4];
  __syncthreads();
  float acc = 0.f;
#pragma unroll 8
  for (int k = 0; k < 512; k++) acc += zs[k] * fc1_wt[k * 128 + tid];
  h1[tid] = fmaxf(acc + fc1_b[tid], 0.f);
  __syncthreads();
  if (tid < 32) {
    float a2 = 0.f;
#pragma unroll 8
    for (int k = 0; k < 128; k++) a2 += h1[k] * fc2_wt[k * 32 + tid];
    h2[tid] = fmaxf(a2 + fc2_b[tid], 0.f);
  }
  __syncthreads();
  if (tid < 2) {
    float a3 = 0.f;
#pragma unroll
    for (int k = 0; k < 32; k++) a3 += h2[k] * fc3_wt[k * 2 + tid];
    out[b * 2 + tid] = fmaxf(a3 + fc3_b[tid], 0.f);
  }
}

// ---------------------------------------------------------------------------
extern "C" void kernel_launch(void* const* d_in, const int* in_sizes, int n_in,
                              void* d_out, int out_size, void* d_ws, size_t ws_size,
                              hipStream_t stream) {
  const float* x     = (const float*)d_in[0];
  const float* w_ih  = (const float*)d_in[1];
  const float* w_hh  = (const float*)d_in[2];
  const float* b_ih  = (const float*)d_in[3];
  const float* b_hh  = (const float*)d_in[4];
  const float* w1    = (const float*)d_in[5];
  const float* b1    = (const float*)d_in[6];
  const float* w2    = (const float*)d_in[7];
  const float* b2    = (const float*)d_in[8];
  const float* w3    = (const float*)d_in[9];
  const float* b3    = (const float*)d_in[10];
  const float* w4    = (const float*)d_in[11];
  const float* b4    = (const float*)d_in[12];
  const float* fc1_w = (const float*)d_in[13];
  const float* fc1_b = (const float*)d_in[14];
  const float* fc2_w = (const float*)d_in[15];
  const float* fc2_b = (const float*)d_in[16];
  const float* fc3_w = (const float*)d_in[17];
  const float* fc3_b = (const float*)d_in[18];
  float* out = (float*)d_out;

  const size_t gfull = (size_t)65536 * 1024, gchunk = (size_t)8192 * 1024;
  const size_t xsf = (size_t)XSP;  // xs = 2*XSP halfs = XSP floats
  const size_t rest = 262144 + 1024 + 3 * 131072 + 262144 + 8388608 + 1048576 +
                      2097152 + 81920 + 49152 + 4096 + 65536 + 4096 + 64 + 786432;
  int full = (ws_size >= (gfull + xsf + rest) * 4) ? 1 : 0;
  size_t gsz = full ? gfull : gchunk;

  float* W = (float*)d_ws;
  size_t o = 0;
  float* gates  = W + o; o += gsz;
  float* w_q    = W + o; o += 262144;
  float* biasg  = W + o; o += 1024;
  float* h_st   = W + o; o += 131072;
  float* c_st   = W + o; o += 131072;
  float* hsum   = W + o; o += 131072;
  float* z      = W + o; o += 262144;
  float* out1   = W + o; o += (size_t)512 * 256 * 64;
  float* out2   = W + o; o += (size_t)512 * 64 * 32;
  float* out3   = W + o; o += (size_t)512 * 256 * 16;
  float* w2t    = W + o; o += 81920;
  float* w3t    = W + o; o += 49152;
  float* w4t    = W + o; o += 4096;
  float* fc1_wt = W + o; o += 65536;
  float* fc2_wt = W + o; o += 4096;
  float* fc3_wt = W + o; o += 64;
  _Float16* wihs = (_Float16*)(W + o); o += 786432;  // 2x1024x768 halfs
  _Float16* xs   = (_Float16*)(W + o); o += xsf;     // 2x65536x768 halfs
  // w1 fp16 split (5.5 MB) aliases out3 (8.4 MB): conv1 reads it strictly
  // before conv3 writes out3 (stream order), so the overlap is safe.
  _Float16* w1s = (_Float16*)out3;
  (void)in_sizes; (void)n_in; (void)out_size;

  xsplit_kernel<<<24576, 256, 0, stream>>>(x, xs);
  prep_kernel<<<5376, 256, 0, stream>>>(w_ih, w_hh, b_ih, b_hh, w1, w2, w3, w4,
                                        fc1_w, fc2_w, fc3_w,
                                        w_q, biasg, w1s, wihs, w2t, w3t, w4t,
                                        fc1_wt, fc2_wt, fc3_wt);
  if (full) {
    gemm_gates_mfma<<<4096, 256, 0, stream>>>(xs, wihs, biasg, gates, 0, 0);
    for (int c = 0; c < NCHUNK; c++)
      lstm_chunk<<<128, 512, 0, stream>>>(gates, w_q, h_st, c_st, hsum, z,
                                          c == 0, c == NCHUNK - 1, 128, c * TCHUNK);
  } else {
    for (int c = 0; c < NCHUNK; c++) {
      gemm_gates_mfma<<<512, 256, 0, stream>>>(xs, wihs, biasg, gates, c * TCHUNK, 1);
      lstm_chunk<<<128, 512, 0, stream>>>(gates, w_q, h_st, c_st, hsum, z,
                                          c == 0, c == NCHUNK - 1, 16, 0);
    }
  }
  conv1_mfma<<<dim3(2, 512), 256, 0, stream>>>(xs, w1s, b1, out1);
  conv2_kernel<<<512, 256, 0, stream>>>(out1, w2t, b2, out2);
  conv3_kernel<<<512, 256, 0, stream>>>(out2, w3t, b3, out3);
  conv4_kernel<<<512, 256, 0, stream>>>(out3, w4t, b4, z);
  head_kernel<<<512, 128, 0, stream>>>(z, fc1_wt, fc1_b, fc2_wt, fc2_b, fc3_wt, fc3_b, out);
}

// Round 5
// 3132.924 us; speedup vs baseline: 2.0674x; 1.1123x over previous
//
#include <hip/hip_runtime.h>

// Model dims
#define BB 512
#define LL 128
#define HH 768
#define LHID 256
#define TCHUNK 16
#define NCHUNK 8

typedef _Float16 h8 __attribute__((ext_vector_type(8)));
typedef _Float16 h4 __attribute__((ext_vector_type(4)));
typedef float f16acc __attribute__((ext_vector_type(16)));

#define APAD 72        // LDS row stride in halfs (gemm)
#define XSP 50331648   // 65536*768, one part of split x

__device__ __forceinline__ float fsig(float x) { return 1.f / (1.f + __expf(-x)); }
__device__ __forceinline__ float ftanh(float x) { return 1.f - 2.f / (__expf(2.f * x) + 1.f); }

// ---------------------------------------------------------------------------
// xsplit: x fp32 -> fp16 hi/lo parts
// ---------------------------------------------------------------------------
__global__ __launch_bounds__(256) void xsplit_kernel(
    const float* __restrict__ x, _Float16* __restrict__ xs) {
  size_t e = ((size_t)blockIdx.x * 256 + threadIdx.x) * 8;
  float4 a = *(const float4*)&x[e];
  float4 b = *(const float4*)&x[e + 4];
  h8 hi, lo;
  hi[0] = (_Float16)a.x; lo[0] = (_Float16)(a.x - (float)hi[0]);
  hi[1] = (_Float16)a.y; lo[1] = (_Float16)(a.y - (float)hi[1]);
  hi[2] = (_Float16)a.z; lo[2] = (_Float16)(a.z - (float)hi[2]);
  hi[3] = (_Float16)a.w; lo[3] = (_Float16)(a.w - (float)hi[3]);
  hi[4] = (_Float16)b.x; lo[4] = (_Float16)(b.x - (float)hi[4]);
  hi[5] = (_Float16)b.y; lo[5] = (_Float16)(b.y - (float)hi[5]);
  hi[6] = (_Float16)b.z; lo[6] = (_Float16)(b.z - (float)hi[6]);
  hi[7] = (_Float16)b.w; lo[7] = (_Float16)(b.w - (float)hi[7]);
  *(h8*)&xs[e] = hi;
  *(h8*)&xs[XSP + e] = lo;
}

// ---------------------------------------------------------------------------
// prep: weight transposes / fp16 splits / LSTM bias fuse
// wihs + biasg are pre-GATHERED: n' = u*4 + gate (so GEMM rows == gates layout)
// ---------------------------------------------------------------------------
__global__ __launch_bounds__(256) void prep_kernel(
    const float* __restrict__ w_ih, const float* __restrict__ w_hh,
    const float* __restrict__ b_ih, const float* __restrict__ b_hh,
    const float* __restrict__ w1, const float* __restrict__ w2, const float* __restrict__ w3,
    const float* __restrict__ w4,
    const float* __restrict__ fc1_w, const float* __restrict__ fc2_w, const float* __restrict__ fc3_w,
    float* __restrict__ w_q, float* __restrict__ biasg,
    _Float16* __restrict__ w1s, _Float16* __restrict__ wihs,
    float* __restrict__ w2t, float* __restrict__ w3t, float* __restrict__ w4t,
    float* __restrict__ fc1_wt, float* __restrict__ fc2_wt, float* __restrict__ fc3_wt) {
  int tid = blockIdx.x * 256 + threadIdx.x;  // grid = 5376*256 = 1376256
  if (tid < 1376256) {  // w1 [co][ci][dk] -> fp16 split hi/lo, layout [dk][co][ci], x64
    int dk = tid / 196608, r = tid % 196608, co = r / 768, ci = r % 768;
    float v = w1[((size_t)co * 768 + ci) * 7 + dk] * 64.f;
    _Float16 h = (_Float16)v;
    w1s[tid] = h;
    w1s[1376256 + tid] = (_Float16)(v - (float)h);
  }
  if (tid < 786432) {  // w_ih -> fp16 split hi/lo, x64, GATHERED rows n' = u*4+gate
    int np = tid / 768, k = tid % 768;
    int u = np >> 2, gate = np & 3;
    float v = w_ih[(size_t)(gate * 256 + u) * 768 + k] * 64.f;
    _Float16 h = (_Float16)v;
    wihs[tid] = h;
    wihs[786432 + tid] = (_Float16)(v - (float)h);
  }
  if (tid < 65536) {  // w_hh [1024][256] -> w_q[k][unit] float4 (i,f,g,o)
    int k = tid >> 8, t = tid & 255;
    float4 wv;
    wv.x = w_hh[(0 * 256 + t) * 256 + k];
    wv.y = w_hh[(1 * 256 + t) * 256 + k];
    wv.z = w_hh[(2 * 256 + t) * 256 + k];
    wv.w = w_hh[(3 * 256 + t) * 256 + k];
    *(float4*)&w_q[tid * 4] = wv;
  }
  if (tid < 1024) {  // gathered bias
    int u = tid >> 2, gate = tid & 3;
    biasg[tid] = b_ih[gate * 256 + u] + b_hh[gate * 256 + u];
  }
  if (tid < 81920) {  // w2 [64co][256ci][5] -> w2t [ci][dk][co]
    int ci = tid / 320, r = tid % 320, dk = r >> 6, co = r & 63;
    w2t[tid] = w2[(co * 256 + ci) * 5 + dk];
  }
  if (tid < 49152) {  // w3 [256co][64ci][3] -> w3t [ci][dk][co]
    int ci = tid / 768, r = tid % 768, dk = r >> 8, co = r & 255;
    w3t[tid] = w3[(co * 64 + ci) * 3 + dk];
  }
  if (tid < 4096) {  // w4 [16co][256ci] -> w4t [ci][co]
    int ci = tid >> 4, co = tid & 15;
    w4t[tid] = w4[co * 256 + ci];
  }
  if (tid < 65536) {  // fc1_w [128][512] -> fc1_wt [512][128]
    int k = tid >> 7, j = tid & 127;
    fc1_wt[tid] = fc1_w[j * 512 + k];
  }
  if (tid < 4096) {  // fc2_w [32][128] -> fc2_wt [128][32]
    int k = tid >> 5, j = tid & 31;
    fc2_wt[tid] = fc2_w[j * 128 + k];
  }
  if (tid < 64) {  // fc3_w [2][32] -> fc3_wt [32][2]
    int k = tid >> 1, j = tid & 1;
    fc3_wt[tid] = fc3_w[j * 32 + k];
  }
}

// ---------------------------------------------------------------------------
// gates GEMM via MFMA fp16x2 split, pre-split inputs, register-prefetch
// double buffer: kc+1's A/B loads issue before kc's compute so HBM latency
// hides under the 48-MFMA block instead of draining at the next ds_write.
// ---------------------------------------------------------------------------
__global__ __launch_bounds__(256, 2) void gemm_gates_mfma(
    const _Float16* __restrict__ xs, const _Float16* __restrict__ wihs,
    const float* __restrict__ biasg, float* __restrict__ gates, int l0, int cmode) {
  __shared__ _Float16 Asp[2][128][APAD];
  __shared__ _Float16 Bsp[2][128][APAD];
  int tid = threadIdx.x;
  int gid = blockIdx.x;
  int mt = (gid & 7) + ((gid >> 6) << 3), nt = (gid >> 3) & 7;
  int m0 = mt << 7, n0 = nt << 7;
  int lane = tid & 63, w = tid >> 6;
  int wm = (w & 1) * 64, wn = (w >> 1) * 64;
  int r32 = lane & 31, hw8 = (lane >> 5) * 8;
  int g8 = (tid & 7) << 3;
  f16acc acc[2][2];
#pragma unroll
  for (int mm = 0; mm < 2; mm++)
#pragma unroll
    for (int nn = 0; nn < 2; nn++) acc[mm][nn] = (f16acc)(0.f);

  // fixed per-thread staging addresses (i-th h8: p = i>>2, row = (i&3)*32 + tid/8)
  size_t abase[8], bbase[8];
#pragma unroll
  for (int i = 0; i < 8; i++) {
    int p = i >> 2, row = (i & 3) * 32 + (tid >> 3);
    int m = m0 + row;
    int xrow = cmode ? (((m >> 4) << 7) + l0 + (m & 15)) : m;
    abase[i] = (size_t)p * XSP + (size_t)xrow * 768 + g8;
    bbase[i] = (size_t)p * 786432 + (size_t)(n0 + row) * 768 + g8;
  }
  h8 ra[8], rb[8];
#pragma unroll
  for (int i = 0; i < 8; i++) {
    ra[i] = *(const h8*)&xs[abase[i]];
    rb[i] = *(const h8*)&wihs[bbase[i]];
  }

  for (int kc = 0; kc < 12; kc++) {
    if (kc) __syncthreads();
#pragma unroll
    for (int i = 0; i < 8; i++) {
      int p = i >> 2, row = (i & 3) * 32 + (tid >> 3);
      *(h8*)&Asp[p][row][g8] = ra[i];
      *(h8*)&Bsp[p][row][g8] = rb[i];
    }
    __syncthreads();
    if (kc < 11) {
      int k0 = (kc + 1) * 64;
#pragma unroll
      for (int i = 0; i < 8; i++) {
        ra[i] = *(const h8*)&xs[abase[i] + k0];
        rb[i] = *(const h8*)&wihs[bbase[i] + k0];
      }
    }
#pragma unroll
    for (int ks = 0; ks < 4; ks++) {
      int k = ks * 16 + hw8;
      h8 ah[2], al[2], bh[2], bl[2];
      ah[0] = *(const h8*)&Asp[0][wm + r32][k];
      ah[1] = *(const h8*)&Asp[0][wm + r32 + 32][k];
      al[0] = *(const h8*)&Asp[1][wm + r32][k];
      al[1] = *(const h8*)&Asp[1][wm + r32 + 32][k];
      bh[0] = *(const h8*)&Bsp[0][wn + r32][k];
      bh[1] = *(const h8*)&Bsp[0][wn + r32 + 32][k];
      bl[0] = *(const h8*)&Bsp[1][wn + r32][k];
      bl[1] = *(const h8*)&Bsp[1][wn + r32 + 32][k];
#pragma unroll
      for (int mm = 0; mm < 2; mm++)
#pragma unroll
        for (int nn = 0; nn < 2; nn++) {
          acc[mm][nn] = __builtin_amdgcn_mfma_f32_32x32x16_f16(ah[mm], bh[nn], acc[mm][nn], 0, 0, 0);
          acc[mm][nn] = __builtin_amdgcn_mfma_f32_32x32x16_f16(ah[mm], bl[nn], acc[mm][nn], 0, 0, 0);
          acc[mm][nn] = __builtin_amdgcn_mfma_f32_32x32x16_f16(al[mm], bh[nn], acc[mm][nn], 0, 0, 0);
        }
    }
  }
  // epilogue: /64, +bias, contiguous row-major stores (full lines)
#pragma unroll
  for (int mm = 0; mm < 2; mm++)
#pragma unroll
    for (int nn = 0; nn < 2; nn++) {
      int n = n0 + wn + nn * 32 + r32;
      float bb = biasg[n];
#pragma unroll
      for (int reg = 0; reg < 16; reg++) {
        int row = (reg & 3) + 8 * (reg >> 2) + (hw8 >> 1);
        int m = m0 + wm + mm * 32 + row;
        gates[(size_t)m * 1024 + n] = acc[mm][nn][reg] * (1.f / 64.f) + bb;
      }
    }
}

// ---------------------------------------------------------------------------
// LSTM full recurrence in ONE launch (full-gates mode): 128 blocks x 512
// threads, block owns 4 batch rows for all 128 steps. k-split halves,
// LDS partial reduce.
// ---------------------------------------------------------------------------
__global__ __launch_bounds__(512) void lstm_full(
    const float* __restrict__ gates, const float* __restrict__ w_q,
    float* __restrict__ z) {
  __shared__ float hl[4][256];
  __shared__ __align__(16) float ps[4][256][4];
  int tid = threadIdx.x;
  int t = tid & 255, half = tid >> 8;
  int r0 = blockIdx.x * 4;
  int rown = half * 2, rother = 2 - rown;
  float c2[2] = {0.f, 0.f}, hs2[2] = {0.f, 0.f};
  hl[rown][t] = 0.f;
  hl[rown + 1][t] = 0.f;
  __syncthreads();
  int kb = half << 7;
  for (int lc = 0; lc < 128; lc++) {
    float4 a[4];
#pragma unroll
    for (int r = 0; r < 4; r++) a[r] = make_float4(0.f, 0.f, 0.f, 0.f);
#pragma unroll 4
    for (int k = 0; k < 128; k++) {
      float4 wv = *(const float4*)&w_q[(size_t)(kb + k) * 1024 + t * 4];
#pragma unroll
      for (int r = 0; r < 4; r++) {
        float hv = hl[r][kb + k];
        a[r].x += hv * wv.x; a[r].y += hv * wv.y;
        a[r].z += hv * wv.z; a[r].w += hv * wv.w;
      }
    }
#pragma unroll
    for (int rr = 0; rr < 2; rr++)
      *(float4*)&ps[rother + rr][t][0] = a[rother + rr];
    __syncthreads();
    float hnew[2];
#pragma unroll
    for (int rr = 0; rr < 2; rr++) {
      int r = rown + rr;
      float4 p = *(const float4*)&ps[r][t][0];
      float4 g4 = *(const float4*)&gates[((size_t)(r0 + r) * 128 + lc) * 1024 + t * 4];
      float gi = a[r].x + p.x + g4.x;
      float gf = a[r].y + p.y + g4.y;
      float gg = a[r].z + p.z + g4.z;
      float go = a[r].w + p.w + g4.w;
      float iv = fsig(gi), fv = fsig(gf), gv = ftanh(gg), ov = fsig(go);
      c2[rr] = fv * c2[rr] + iv * gv;
      float hv = ov * ftanh(c2[rr]);
      hs2[rr] += hv;
      hnew[rr] = hv;
    }
#pragma unroll
    for (int rr = 0; rr < 2; rr++) hl[rown + rr][t] = hnew[rr];
    __syncthreads();
  }
#pragma unroll
  for (int rr = 0; rr < 2; rr++)
    z[(size_t)(r0 + rown + rr) * 512 + t] = hs2[rr] * (1.f / 128.f);
}

// ---------------------------------------------------------------------------
// LSTM chunked fallback (16 steps per launch) — used only if ws too small
// ---------------------------------------------------------------------------
__global__ __launch_bounds__(512) void lstm_chunk(
    const float* __restrict__ gates, const float* __restrict__ w_q,
    float* __restrict__ h_state, float* __restrict__ c_state, float* __restrict__ hsum,
    float* __restrict__ z, int first, int last, int gB, int l0f) {
  __shared__ float hl[4][256];
  __shared__ __align__(16) float ps[4][256][4];
  int tid = threadIdx.x;
  int t = tid & 255, half = tid >> 8;
  int r0 = blockIdx.x * 4;
  int rown = half * 2, rother = 2 - rown;
  float c2[2], hs2[2];
#pragma unroll
  for (int rr = 0; rr < 2; rr++) {
    int r = rown + rr;
    float hv;
    if (first) { hv = 0.f; c2[rr] = 0.f; hs2[rr] = 0.f; }
    else {
      hv = h_state[(r0 + r) * 256 + t];
      c2[rr] = c_state[(r0 + r) * 256 + t];
      hs2[rr] = hsum[(r0 + r) * 256 + t];
    }
    hl[r][t] = hv;
  }
  __syncthreads();
  int kb = half << 7;
  for (int lc = 0; lc < TCHUNK; lc++) {
    float4 a[4];
#pragma unroll
    for (int r = 0; r < 4; r++) a[r] = make_float4(0.f, 0.f, 0.f, 0.f);
#pragma unroll 4
    for (int k = 0; k < 128; k++) {
      float4 wv = *(const float4*)&w_q[(size_t)(kb + k) * 1024 + t * 4];
#pragma unroll
      for (int r = 0; r < 4; r++) {
        float hv = hl[r][kb + k];
        a[r].x += hv * wv.x; a[r].y += hv * wv.y;
        a[r].z += hv * wv.z; a[r].w += hv * wv.w;
      }
    }
#pragma unroll
    for (int rr = 0; rr < 2; rr++)
      *(float4*)&ps[rother + rr][t][0] = a[rother + rr];
    __syncthreads();
    float hnew[2];
#pragma unroll
    for (int rr = 0; rr < 2; rr++) {
      int r = rown + rr;
      float4 p = *(const float4*)&ps[r][t][0];
      float4 g4 = *(const float4*)&gates[((size_t)(r0 + r) * gB + l0f + lc) * 1024 + t * 4];
      float gi = a[r].x + p.x + g4.x;
      float gf = a[r].y + p.y + g4.y;
      float gg = a[r].z + p.z + g4.z;
      float go = a[r].w + p.w + g4.w;
      float iv = fsig(gi), fv = fsig(gf), gv = ftanh(gg), ov = fsig(go);
      c2[rr] = fv * c2[rr] + iv * gv;
      float hv = ov * ftanh(c2[rr]);
      hs2[rr] += hv;
      hnew[rr] = hv;
    }
#pragma unroll
    for (int rr = 0; rr < 2; rr++) hl[rown + rr][t] = hnew[rr];
    __syncthreads();
  }
#pragma unroll
  for (int rr = 0; rr < 2; rr++) {
    int r = rown + rr;
    h_state[(r0 + r) * 256 + t] = hl[r][t];
    c_state[(r0 + r) * 256 + t] = c2[rr];
    hsum[(r0 + r) * 256 + t] = hs2[rr];
    if (last) z[(r0 + r) * 512 + t] = hs2[rr] * (1.f / 128.f);
  }
}

// ---------------------------------------------------------------------------
// conv1 v3 via MFMA fp16x2: co=64/block, ci-chunk=32, B staged for ALL 7 dk
// at once -> 2 barriers per ci-chunk (48/block) instead of 14 (168/block).
// Block tile M=128 l-rows (halo 134) x N=64 co. 4 waves of 64x32.
// ---------------------------------------------------------------------------
__global__ __launch_bounds__(256, 2) void conv1_mfma(
    const _Float16* __restrict__ xs, const _Float16* __restrict__ w1s,
    const float* __restrict__ b1, float* __restrict__ out1) {
  __shared__ _Float16 Asp[2][134][36];   // [p][x row l0-3..l0+130][ci 32]
  __shared__ _Float16 Bsp[2][64][228];   // [p][co][k=dk*32+ci, 224]
  int tid = threadIdx.x;
  int b = blockIdx.y;
  int co0 = blockIdx.x << 6;
  int lane = tid & 63, w = tid >> 6;
  int wm = (w & 1) * 64, wn = (w >> 1) * 32;
  int r32 = lane & 31, hw8 = (lane >> 5) * 8;
  f16acc acc[2];
  acc[0] = (f16acc)(0.f);
  acc[1] = (f16acc)(0.f);

  for (int cc = 0; cc < 24; cc++) {
    int ci0 = cc * 32;
    if (cc) __syncthreads();
    // stage A: 2p x 134 rows x 4 h8 = 1072
    for (int f = tid; f < 1072; f += 256) {
      int p = f >= 536;
      int r = f - p * 536;
      int row = r >> 2, g = (r & 3) << 3;
      int l = row - 3;
      h8 v = (h8)(_Float16)0.f;
      if (l >= 0 && l < 128)
        v = *(const h8*)&xs[(size_t)p * XSP + ((size_t)b * 128 + l) * 768 + ci0 + g];
      *(h8*)&Asp[p][row][g] = v;
    }
    // stage B: 2p x 64 co x 28 h8 (all 7 dk) = 3584
    for (int f = tid; f < 3584; f += 256) {
      int p = f >= 1792;
      int r = f - p * 1792;
      int co = r / 28, gg = r - co * 28;
      int k = gg << 3;
      int dk = k >> 5, ci = k & 31;
      *(h8*)&Bsp[p][co][k] =
          *(const h8*)&w1s[(size_t)p * 1376256 + ((size_t)dk * 256 + co0 + co) * 768 + ci0 + ci];
    }
    __syncthreads();
#pragma unroll
    for (int ks = 0; ks < 14; ks++) {
      int dk = ks >> 1;
      int cib = ((ks & 1) << 4) + hw8;
      int kb = ks * 16 + hw8;
      h8 ah[2], al[2], bh, bl;
      ah[0] = *(const h8*)&Asp[0][wm + r32 + dk][cib];
      ah[1] = *(const h8*)&Asp[0][wm + 32 + r32 + dk][cib];
      al[0] = *(const h8*)&Asp[1][wm + r32 + dk][cib];
      al[1] = *(const h8*)&Asp[1][wm + 32 + r32 + dk][cib];
      bh = *(const h8*)&Bsp[0][wn + r32][kb];
      bl = *(const h8*)&Bsp[1][wn + r32][kb];
#pragma unroll
      for (int mm = 0; mm < 2; mm++) {
        acc[mm] = __builtin_amdgcn_mfma_f32_32x32x16_f16(ah[mm], bh, acc[mm], 0, 0, 0);
        acc[mm] = __builtin_amdgcn_mfma_f32_32x32x16_f16(ah[mm], bl, acc[mm], 0, 0, 0);
        acc[mm] = __builtin_amdgcn_mfma_f32_32x32x16_f16(al[mm], bh, acc[mm], 0, 0, 0);
      }
    }
  }
  // epilogue: /64, +bias, pool adjacent l rows (adjacent acc regs), relu
  int co = co0 + wn + r32;
  float bb = b1[co];
  size_t obase = ((size_t)b * 256 + co) * 64;
#pragma unroll
  for (int mm = 0; mm < 2; mm++) {
#pragma unroll
    for (int i = 0; i < 8; i++) {
      int rb = ((i & 1) << 1) + ((i >> 1) << 3) + (hw8 >> 1);
      float v = fmaxf(acc[mm][2 * i], acc[mm][2 * i + 1]) * (1.f / 64.f) + bb;
      out1[obase + ((wm + mm * 32 + rb) >> 1)] = fmaxf(v, 0.f);
    }
  }
}

// ---------------------------------------------------------------------------
// conv2 (256->64, K=5, pad2) + pool2 + relu -> out2 [512][64][32]
// ---------------------------------------------------------------------------
__global__ __launch_bounds__(256) void conv2_kernel(
    const float* __restrict__ out1, const float* __restrict__ w2t,
    const float* __restrict__ b2, float* __restrict__ out2) {
  __shared__ float X2[32 * 68];
  __shared__ __align__(16) float W2[32 * 5 * 64];
  int tid = threadIdx.x;
  int b = blockIdx.x;
  int co = tid & 63, pg = tid >> 6;
  float acc[16] = {};
  for (int c0 = 0; c0 < 256; c0 += 32) {
    for (int f = tid; f < 512; f += 256) {
      int ci = f >> 4, q = (f & 15) << 2;
      float4 v = *(const float4*)&out1[(b * 256 + c0 + ci) * 64 + q];
      X2[ci * 68 + 2 + q + 0] = v.x; X2[ci * 68 + 2 + q + 1] = v.y;
      X2[ci * 68 + 2 + q + 2] = v.z; X2[ci * 68 + 2 + q + 3] = v.w;
    }
    if (tid < 32) { X2[tid * 68] = 0.f; X2[tid * 68 + 1] = 0.f; X2[tid * 68 + 66] = 0.f; X2[tid * 68 + 67] = 0.f; }
    for (int f = tid; f < 2560; f += 256)
      *(float4*)&W2[f * 4] = *(const float4*)&w2t[c0 * 320 + f * 4];
    __syncthreads();
    for (int ci = 0; ci < 32; ci++) {
      float xv[20];
#pragma unroll
      for (int u = 0; u < 20; u++) xv[u] = X2[ci * 68 + pg * 16 + u];
#pragma unroll
      for (int dk = 0; dk < 5; dk++) {
        float w = W2[(ci * 5 + dk) * 64 + co];
#pragma unroll
        for (int i = 0; i < 16; i++) acc[i] += xv[i + dk] * w;
      }
    }
    __syncthreads();
  }
  float bb = b2[co];
#pragma unroll
  for (int p = 0; p < 8; p++) {
    float v = fmaxf(acc[2 * p], acc[2 * p + 1]) + bb;
    out2[(b * 64 + co) * 32 + pg * 8 + p] = fmaxf(v, 0.f);
  }
}

// ---------------------------------------------------------------------------
// conv3 (64->256, K=3, pad1) + pool2 + relu -> out3 [512][256][16]
// ---------------------------------------------------------------------------
__global__ __launch_bounds__(256) void conv3_kernel(
    const float* __restrict__ out2, const float* __restrict__ w3t,
    const float* __restrict__ b3, float* __restrict__ out3) {
  __shared__ float X3[64 * 34];
  __shared__ __align__(16) float W3[16 * 3 * 256];
  int tid = threadIdx.x;
  int b = blockIdx.x;
  float acc[32] = {};
  for (int f = tid; f < 512; f += 256) {
    int ci = f >> 3, q = (f & 7) << 2;
    float4 v = *(const float4*)&out2[(b * 64 + ci) * 32 + q];
    X3[ci * 34 + 1 + q + 0] = v.x; X3[ci * 34 + 1 + q + 1] = v.y;
    X3[ci * 34 + 1 + q + 2] = v.z; X3[ci * 34 + 1 + q + 3] = v.w;
  }
  if (tid < 64) { X3[tid * 34] = 0.f; X3[tid * 34 + 33] = 0.f; }
  __syncthreads();
  for (int c0 = 0; c0 < 64; c0 += 16) {
    for (int f = tid; f < 3072; f += 256)
      *(float4*)&W3[f * 4] = *(const float4*)&w3t[c0 * 768 + f * 4];
    __syncthreads();
    for (int ci = 0; ci < 16; ci++) {
      float xv[34];
#pragma unroll
      for (int u = 0; u < 34; u++) xv[u] = X3[(c0 + ci) * 34 + u];
#pragma unroll
      for (int dk = 0; dk < 3; dk++) {
        float w = W3[(ci * 3 + dk) * 256 + tid];
#pragma unroll
        for (int i = 0; i < 32; i++) acc[i] += xv[i + dk] * w;
      }
    }
    __syncthreads();
  }
  float bb = b3[tid];
#pragma unroll
  for (int p = 0; p < 16; p++) {
    float v = fmaxf(acc[2 * p], acc[2 * p + 1]) + bb;
    out3[(b * 256 + tid) * 16 + p] = fmaxf(v, 0.f);
  }
}

// ---------------------------------------------------------------------------
// conv4 (256->16, K=1) + relu -> z[:, 256:512]
// ---------------------------------------------------------------------------
__global__ __launch_bounds__(256) void conv4_kernel(
    const float* __restrict__ out3, const float* __restrict__ w4t,
    const float* __restrict__ b4, float* __restrict__ z) {
  __shared__ __align__(16) float X4[256 * 16];
  __shared__ __align__(16) float W4[256 * 16];
  int tid = threadIdx.x;
  int b = blockIdx.x;
  for (int f = tid; f < 1024; f += 256) {
    *(float4*)&X4[f * 4] = *(const float4*)&out3[b * 4096 + f * 4];
    *(float4*)&W4[f * 4] = *(const float4*)&w4t[f * 4];
  }
  __syncthreads();
  int co = tid >> 4, l = tid & 15;
  float acc = 0.f;
#pragma unroll 8
  for (int ci = 0; ci < 256; ci++) acc += X4[ci * 16 + l] * W4[ci * 16 + co];
  z[b * 512 + 256 + tid] = fmaxf(acc + b4[co], 0.f);
}

// ---------------------------------------------------------------------------
// MLP head
// ---------------------------------------------------------------------------
__global__ __launch_bounds__(128) void head_kernel(
    const float* __restrict__ z,
    const float* __restrict__ fc1_wt, const float* __restrict__ fc1_b,
    const float* __restrict__ fc2_wt, const float* __restrict__ fc2_b,
    const float* __restrict__ fc3_wt, const float* __restrict__ fc3_b,
    float* __restrict__ out) {
  __shared__ __align__(16) float zs[512];
  __shared__ float h1[128];
  __shared__ float h2[32];
  int tid = threadIdx.x;
  int b = blockIdx.x;
  *(float4*)&zs[tid * 4] = *(const float4*)&z[b * 512 + tid * 4];
  __syncthreads();
  float acc = 0.f;
#pragma unroll 8
  for (int k = 0; k < 512; k++) acc += zs[k] * fc1_wt[k * 128 + tid];
  h1[tid] = fmaxf(acc + fc1_b[tid], 0.f);
  __syncthreads();
  if (tid < 32) {
    float a2 = 0.f;
#pragma unroll 8
    for (int k = 0; k < 128; k++) a2 += h1[k] * fc2_wt[k * 32 + tid];
    h2[tid] = fmaxf(a2 + fc2_b[tid], 0.f);
  }
  __syncthreads();
  if (tid < 2) {
    float a3 = 0.f;
#pragma unroll
    for (int k = 0; k < 32; k++) a3 += h2[k] * fc3_wt[k * 2 + tid];
    out[b * 2 + tid] = fmaxf(a3 + fc3_b[tid], 0.f);
  }
}

// ---------------------------------------------------------------------------
extern "C" void kernel_launch(void* const* d_in, const int* in_sizes, int n_in,
                              void* d_out, int out_size, void* d_ws, size_t ws_size,
                              hipStream_t stream) {
  const float* x     = (const float*)d_in[0];
  const float* w_ih  = (const float*)d_in[1];
  const float* w_hh  = (const float*)d_in[2];
  const float* b_ih  = (const float*)d_in[3];
  const float* b_hh  = (const float*)d_in[4];
  const float* w1    = (const float*)d_in[5];
  const float* b1    = (const float*)d_in[6];
  const float* w2    = (const float*)d_in[7];
  const float* b2    = (const float*)d_in[8];
  const float* w3    = (const float*)d_in[9];
  const float* b3    = (const float*)d_in[10];
  const float* w4    = (const float*)d_in[11];
  const float* b4    = (const float*)d_in[12];
  const float* fc1_w = (const float*)d_in[13];
  const float* fc1_b = (const float*)d_in[14];
  const float* fc2_w = (const float*)d_in[15];
  const float* fc2_b = (const float*)d_in[16];
  const float* fc3_w = (const float*)d_in[17];
  const float* fc3_b = (const float*)d_in[18];
  float* out = (float*)d_out;

  const size_t gfull = (size_t)65536 * 1024, gchunk = (size_t)8192 * 1024;
  const size_t xsf = (size_t)XSP;  // xs = 2*XSP halfs = XSP floats
  const size_t rest = 262144 + 1024 + 3 * 131072 + 262144 + 8388608 + 1048576 +
                      2097152 + 81920 + 49152 + 4096 + 65536 + 4096 + 64 + 786432;
  int full = (ws_size >= (gfull + xsf + rest) * 4) ? 1 : 0;
  size_t gsz = full ? gfull : gchunk;

  float* W = (float*)d_ws;
  size_t o = 0;
  float* gates  = W + o; o += gsz;
  float* w_q    = W + o; o += 262144;
  float* biasg  = W + o; o += 1024;
  float* h_st   = W + o; o += 131072;
  float* c_st   = W + o; o += 131072;
  float* hsum   = W + o; o += 131072;
  float* z      = W + o; o += 262144;
  float* out1   = W + o; o += (size_t)512 * 256 * 64;
  float* out2   = W + o; o += (size_t)512 * 64 * 32;
  float* out3   = W + o; o += (size_t)512 * 256 * 16;
  float* w2t    = W + o; o += 81920;
  float* w3t    = W + o; o += 49152;
  float* w4t    = W + o; o += 4096;
  float* fc1_wt = W + o; o += 65536;
  float* fc2_wt = W + o; o += 4096;
  float* fc3_wt = W + o; o += 64;
  _Float16* wihs = (_Float16*)(W + o); o += 786432;  // 2x1024x768 halfs
  _Float16* xs   = (_Float16*)(W + o); o += xsf;     // 2x65536x768 halfs
  // w1 fp16 split (5.5 MB) aliases out3 (8.4 MB): conv1 reads it strictly
  // before conv3 writes out3 (stream order), so the overlap is safe.
  _Float16* w1s = (_Float16*)out3;
  (void)in_sizes; (void)n_in; (void)out_size;

  xsplit_kernel<<<24576, 256, 0, stream>>>(x, xs);
  prep_kernel<<<5376, 256, 0, stream>>>(w_ih, w_hh, b_ih, b_hh, w1, w2, w3, w4,
                                        fc1_w, fc2_w, fc3_w,
                                        w_q, biasg, w1s, wihs, w2t, w3t, w4t,
                                        fc1_wt, fc2_wt, fc3_wt);
  if (full) {
    gemm_gates_mfma<<<4096, 256, 0, stream>>>(xs, wihs, biasg, gates, 0, 0);
    lstm_full<<<128, 512, 0, stream>>>(gates, w_q, z);
  } else {
    for (int c = 0; c < NCHUNK; c++) {
      gemm_gates_mfma<<<512, 256, 0, stream>>>(xs, wihs, biasg, gates, c * TCHUNK, 1);
      lstm_chunk<<<128, 512, 0, stream>>>(gates, w_q, h_st, c_st, hsum, z,
                                          c == 0, c == NCHUNK - 1, 16, 0);
    }
  }
  conv1_mfma<<<dim3(4, 512), 256, 0, stream>>>(xs, w1s, b1, out1);
  conv2_kernel<<<512, 256, 0, stream>>>(out1, w2t, b2, out2);
  conv3_kernel<<<512, 256, 0, stream>>>(out2, w3t, b3, out3);
  conv4_kernel<<<512, 256, 0, stream>>>(out3, w4t, b4, z);
  head_kernel<<<512, 128, 0, stream>>>(z, fc1_wt, fc1_b, fc2_wt, fc2_b, fc3_wt, fc3_b, out);
}